// Round 1
// baseline (708.524 us; speedup 1.0000x reference)
//
#include <hip/hip_runtime.h>
#include <stdint.h>

#define NLOC   21824
#define BATCH  8
#define MAXDET 1000
#define NCLS   80

struct LevelPtrs {
    const float* cls[5];
    const float* cnt[5];
    const float* reg[5];
};

__device__ inline uint64_t shfl64(uint64_t v, int lane) {
    int lo = __shfl((int)(uint32_t)(v & 0xffffffffull), lane, 64);
    int hi = __shfl((int)(uint32_t)(v >> 32), lane, 64);
    return ((uint64_t)(uint32_t)hi << 32) | (uint32_t)(uint32_t)lo;
}

// ---------------------------------------------------------------------------
// K1: per-location score / class / box
// ---------------------------------------------------------------------------
__global__ __launch_bounds__(256) void k_stage1(LevelPtrs lp, float* scores,
                                                int* cls_out, float4* boxes) {
    int n = blockIdx.x * 256 + threadIdx.x;
    int b = blockIdx.y;
    if (n >= NLOC) return;

    int lvl, off, logw, strd;
    if (n < 16384)      { lvl = 0; off = 0;     logw = 7; strd = 8;   }
    else if (n < 20480) { lvl = 1; off = 16384; logw = 6; strd = 16;  }
    else if (n < 21504) { lvl = 2; off = 20480; logw = 5; strd = 32;  }
    else if (n < 21760) { lvl = 3; off = 21504; logw = 4; strd = 64;  }
    else                { lvl = 4; off = 21760; logw = 3; strd = 128; }

    int loc = n - off;
    int hw  = 1 << (2 * logw);
    int x   = loc & ((1 << logw) - 1);
    int y   = loc >> logw;

    // argmax over sigmoid(cls logits), first-index tie-break (matches jnp.argmax)
    const float* cp = lp.cls[lvl] + (size_t)(b * NCLS) * hw + loc;
    float l0 = cp[0];
    float e_best = expf(-l0);
    float best_sig = 1.0f / (1.0f + e_best);
    int best_c = 0;
    for (int c = 1; c < NCLS; ++c) {
        float l = cp[(size_t)c * hw];
        float e = expf(-l);
        if (e < e_best) {                 // sigmoid monotone: only then can it beat best
            float sg = 1.0f / (1.0f + e);
            if (sg > best_sig) { best_sig = sg; best_c = c; }
            e_best = e;
        }
    }
    float lc = lp.cnt[lvl][(size_t)b * hw + loc];
    float sig_cnt = 1.0f / (1.0f + expf(-lc));
    float score = sqrtf(__fmul_rn(best_sig, sig_cnt));

    const float* rp = lp.reg[lvl] + (size_t)(b * 4) * hw + loc;
    float r0 = rp[0], r1 = rp[(size_t)hw], r2 = rp[(size_t)2 * hw], r3 = rp[(size_t)3 * hw];
    float cx = (float)(x * strd + (strd >> 1));
    float cy = (float)(y * strd + (strd >> 1));
    float4 bx = make_float4(__fsub_rn(cx, r0), __fsub_rn(cy, r1),
                            __fadd_rn(cx, r2), __fadd_rn(cy, r3));

    int o = b * NLOC + n;
    scores[o]  = score;
    cls_out[o] = best_c + 1;
    boxes[o]   = bx;
}

// ---------------------------------------------------------------------------
// K2: per-batch exact top-1000 (stable desc by (score, -idx)) via radix-select
// ---------------------------------------------------------------------------
__global__ __launch_bounds__(256) void k_select(const uint32_t* scores_u,
                                                float* topk_score, int* topk_idx) {
    __shared__ uint32_t hist[256];
    __shared__ uint64_t keys[2048];
    __shared__ uint32_t prefix_sh, cnt_sh;
    __shared__ int R_sh;

    int b = blockIdx.x, tid = threadIdx.x;
    const uint32_t* sc = scores_u + (size_t)b * NLOC;

    uint32_t prefix = 0;
    int R = MAXDET;
    for (int d = 3; d >= 0; --d) {
        hist[tid] = 0;
        __syncthreads();
        int shl = 8 * d;
        int last = -1; uint32_t run = 0;
        for (int n = tid; n < NLOC; n += 256) {
            uint32_t sb = sc[n];
            bool m = (d == 3) || ((sb >> (shl + 8)) == prefix);
            int dig = m ? (int)((sb >> shl) & 255u) : -1;
            if (dig != last) {
                if (last >= 0 && run) atomicAdd(&hist[last], run);
                last = dig; run = 0;
            }
            if (dig >= 0) run++;
        }
        if (last >= 0 && run) atomicAdd(&hist[last], run);
        __syncthreads();
        if (tid == 0) {
            int cum = 0, dsel = 0;
            for (int dg = 255; dg >= 0; --dg) {
                int c = (int)hist[dg];
                if (cum + c >= R) { dsel = dg; R_sh = R - cum; break; }
                cum += c;
            }
            prefix_sh = (prefix << 8) | (uint32_t)dsel;
        }
        __syncthreads();
        prefix = prefix_sh;
        R = R_sh;
        __syncthreads();
    }
    uint32_t Sstar = prefix;

    if (tid == 0) cnt_sh = 0;
    __syncthreads();
    for (int n = tid; n < NLOC; n += 256) {
        uint32_t sb = sc[n];
        if (sb >= Sstar) {
            uint32_t slot = atomicAdd(&cnt_sh, 1u);
            if (slot < 2048)
                keys[slot] = ((uint64_t)sb << 32) | (uint32_t)(~(uint32_t)n);
        }
    }
    __syncthreads();
    uint32_t cnt = cnt_sh > 2048u ? 2048u : cnt_sh;
    for (int i = tid; i < 2048; i += 256)
        if (i >= (int)cnt) keys[i] = 0;
    __syncthreads();

    // bitonic sort, descending
    for (int k = 2; k <= 2048; k <<= 1) {
        for (int j = k >> 1; j > 0; j >>= 1) {
            for (int i = tid; i < 2048; i += 256) {
                int l = i ^ j;
                if (l > i) {
                    uint64_t a = keys[i], c = keys[l];
                    bool desc = ((i & k) == 0);
                    if (desc ? (a < c) : (a > c)) { keys[i] = c; keys[l] = a; }
                }
            }
            __syncthreads();
        }
    }
    for (int r = tid; r < MAXDET; r += 256) {
        uint64_t key = keys[r];
        topk_score[b * MAXDET + r] = __uint_as_float((uint32_t)(key >> 32));
        topk_idx[b * MAXDET + r]   = (int)(~(uint32_t)key);
    }
}

// ---------------------------------------------------------------------------
// K3: gather topk, per-batch maxc, class-offset boxes + areas
// ---------------------------------------------------------------------------
__global__ __launch_bounds__(256) void k_prep(const float4* boxes, const int* cls_ws,
                                              const int* topk_idx, float4* gbox,
                                              int* gcls, float4* obox, float* areas) {
    __shared__ float red[256];
    int b = blockIdx.x, tid = threadIdx.x;

    float4 bx[4]; int cls4[4];
    float m = -3.0e38f;
    for (int q = 0; q < 4; ++q) {
        int r = tid + q * 256;
        if (r < MAXDET) {
            int idx = topk_idx[b * MAXDET + r];
            float4 v = boxes[(size_t)b * NLOC + idx];
            bx[q] = v;
            cls4[q] = cls_ws[(size_t)b * NLOC + idx];
            m = fmaxf(m, fmaxf(fmaxf(v.x, v.y), fmaxf(v.z, v.w)));
        }
    }
    red[tid] = m;
    __syncthreads();
    for (int s = 128; s > 0; s >>= 1) {
        if (tid < s) red[tid] = fmaxf(red[tid], red[tid + s]);
        __syncthreads();
    }
    float maxc1 = __fadd_rn(red[0], 1.0f);

    for (int q = 0; q < 4; ++q) {
        int r = tid + q * 256;
        if (r < MAXDET) {
            float off = __fmul_rn((float)cls4[q], maxc1);
            float4 v = bx[q];
            float4 o = make_float4(__fadd_rn(v.x, off), __fadd_rn(v.y, off),
                                   __fadd_rn(v.z, off), __fadd_rn(v.w, off));
            obox[b * MAXDET + r] = o;
            areas[b * MAXDET + r] =
                __fmul_rn(__fadd_rn(__fsub_rn(o.z, o.x), 1.0f),
                          __fadd_rn(__fsub_rn(o.w, o.y), 1.0f));
            gbox[b * MAXDET + r] = v;
            gcls[b * MAXDET + r] = cls4[q];
        }
    }
}

// ---------------------------------------------------------------------------
// K4: suppression bit-matrix rows (j > i), iou > 0.6 as inter > 0.6*denom
// ---------------------------------------------------------------------------
__global__ __launch_bounds__(256) void k_iou(const float4* obox, const float* areas,
                                             uint64_t* rows) {
    __shared__ float4 ob[MAXDET];
    __shared__ float  ar[MAXDET];
    int b = blockIdx.x, tid = threadIdx.x;
    for (int r = tid; r < MAXDET; r += 256) {
        ob[r] = obox[b * MAXDET + r];
        ar[r] = areas[b * MAXDET + r];
    }
    __syncthreads();
    int i = blockIdx.y * 256 + tid;
    if (i >= MAXDET) return;
    float4 bi = ob[i];
    float ai = ar[i];
    uint64_t row[16];
#pragma unroll
    for (int w = 0; w < 16; ++w) row[w] = 0;
    for (int j = i + 1; j < MAXDET; ++j) {
        float4 bj = ob[j];
        float xx1 = fmaxf(bi.x, bj.x), yy1 = fmaxf(bi.y, bj.y);
        float xx2 = fminf(bi.z, bj.z), yy2 = fminf(bi.w, bj.w);
        float w_ = fmaxf(__fsub_rn(xx2, xx1), 0.0f);
        float h_ = fmaxf(__fsub_rn(yy2, yy1), 0.0f);
        float inter = __fmul_rn(w_, h_);
        float denom = __fsub_rn(__fadd_rn(ai, ar[j]), inter);
        if (inter > __fmul_rn(0.6f, denom)) row[j >> 6] |= (1ull << (j & 63));
    }
    uint64_t* rp = rows + ((size_t)(b * MAXDET) + i) * 16;
#pragma unroll
    for (int w = 0; w < 16; ++w) rp[w] = row[w];
}

// ---------------------------------------------------------------------------
// K5: sequential greedy scan (wave 0, 16 mask lanes) + final outputs
// ---------------------------------------------------------------------------
__global__ __launch_bounds__(256) void k_nms_out(const uint64_t* rows,
                                                 const float* topk_score,
                                                 const int* gcls, const float4* gbox,
                                                 float* out) {
    __shared__ uint64_t rows_lds[8000];   // 500 rows x 16 words = 64000 B
    __shared__ uint64_t validmask[16];
    __shared__ uint64_t keepmask[16];
    int b = blockIdx.x, tid = threadIdx.x;

    if (tid < 16) validmask[tid] = 0;
    __syncthreads();
    for (int r = tid; r < MAXDET; r += 256)
        if (topk_score[b * MAXDET + r] >= 0.05f)
            atomicOr(&validmask[r >> 6], 1ull << (r & 63));
    __syncthreads();

    uint64_t S_reg = 0, K_reg = 0, V_reg = 0;
    if (tid < 16) V_reg = validmask[tid];

    for (int p = 0; p < 2; ++p) {
        for (int w = tid; w < 8000; w += 256)
            rows_lds[w] = rows[((size_t)(b * MAXDET) + p * 500) * 16 + w];
        __syncthreads();
        if (tid < 64) {
            for (int ii = 0; ii < 500; ++ii) {
                int gi = p * 500 + ii;
                int word = gi >> 6, bitp = gi & 63;
                uint64_t sw = shfl64(S_reg, word);
                uint64_t vw = shfl64(V_reg, word);
                bool alive = (((vw >> bitp) & 1ull) != 0) && (((sw >> bitp) & 1ull) == 0);
                if (alive) {
                    uint64_t rw = (tid < 16) ? rows_lds[ii * 16 + tid] : 0ull;
                    S_reg |= rw;
                    if (tid == word) K_reg |= (1ull << bitp);
                }
            }
        }
        __syncthreads();
    }
    if (tid < 16) keepmask[tid] = K_reg;
    __syncthreads();

    for (int r = tid; r < MAXDET; r += 256) {
        bool keep = ((keepmask[r >> 6] >> (r & 63)) & 1ull) != 0;
        float sc = topk_score[b * MAXDET + r];
        int cl = gcls[b * MAXDET + r];
        float4 v = gbox[b * MAXDET + r];
        float c0 = fminf(fmaxf(v.x, 0.0f), 1023.0f);
        float c1 = fminf(fmaxf(v.y, 0.0f), 1023.0f);
        float c2 = fminf(fmaxf(v.z, 0.0f), 1023.0f);
        float c3 = fminf(fmaxf(v.w, 0.0f), 1023.0f);
        out[b * MAXDET + r] = keep ? sc : 0.0f;
        out[BATCH * MAXDET + b * MAXDET + r] = keep ? (float)cl : 0.0f;
        float4* op = (float4*)(out + 2 * BATCH * MAXDET) + (b * MAXDET + r);
        *op = keep ? make_float4(c0, c1, c2, c3) : make_float4(0.f, 0.f, 0.f, 0.f);
    }
}

// ---------------------------------------------------------------------------
extern "C" void kernel_launch(void* const* d_in, const int* in_sizes, int n_in,
                              void* d_out, int out_size, void* d_ws, size_t ws_size,
                              hipStream_t stream) {
    (void)in_sizes; (void)n_in; (void)out_size; (void)ws_size;

    LevelPtrs lp;
    for (int i = 0; i < 5; ++i) {
        lp.cls[i] = (const float*)d_in[3 * i + 0];
        lp.cnt[i] = (const float*)d_in[3 * i + 1];
        lp.reg[i] = (const float*)d_in[3 * i + 2];
    }

    char* ws = (char*)d_ws;
    // ws layout (all 16B-aligned where needed); total ~5.6 MB
    float*    scores   = (float*)   (ws + 0);          // 8*21824*4   = 698368
    int*      cls_ws   = (int*)     (ws + 698368);     // 698368
    float4*   boxes    = (float4*)  (ws + 1396736);    // 8*21824*16  = 2793472
    int*      topk_idx = (int*)     (ws + 4190208);    // 32000
    float*    topk_sc  = (float*)   (ws + 4222208);    // 32000
    int*      gcls     = (int*)     (ws + 4254208);    // 32000
    float4*   gbox     = (float4*)  (ws + 4286208);    // 128000
    float4*   obox     = (float4*)  (ws + 4414208);    // 128000
    float*    areas    = (float*)   (ws + 4542208);    // 32000
    uint64_t* rows     = (uint64_t*)(ws + 4574208);    // 8*1000*16*8 = 1024000

    dim3 g1((NLOC + 255) / 256, BATCH);
    k_stage1<<<g1, 256, 0, stream>>>(lp, scores, cls_ws, boxes);

    k_select<<<BATCH, 256, 0, stream>>>((const uint32_t*)scores, topk_sc, topk_idx);

    k_prep<<<BATCH, 256, 0, stream>>>(boxes, cls_ws, topk_idx, gbox, gcls, obox, areas);

    dim3 g4(BATCH, 4);
    k_iou<<<g4, 256, 0, stream>>>(obox, areas, rows);

    k_nms_out<<<BATCH, 256, 0, stream>>>(rows, topk_sc, gcls, gbox, (float*)d_out);
}

// Round 3
// 505.491 us; speedup vs baseline: 1.4017x; 1.4017x over previous
//
#include <hip/hip_runtime.h>
#include <stdint.h>

#define NLOC   21824
#define NQUAD  5456          // NLOC/4
#define BATCH  8
#define MAXDET 1000
#define NCLS   80

struct LevelPtrs {
    const float* cls[5];
    const float* cnt[5];
    const float* reg[5];
};

__device__ inline uint64_t shfl64(uint64_t v, int lane) {
    int lo = __shfl((int)(uint32_t)(v & 0xffffffffull), lane, 64);
    int hi = __shfl((int)(uint32_t)(v >> 32), lane, 64);
    return ((uint64_t)(uint32_t)hi << 32) | (uint32_t)(uint32_t)lo;
}

// ---------------------------------------------------------------------------
// K1: per-location score / class / box — 4 locations per thread, float4 loads
// ---------------------------------------------------------------------------
__global__ __launch_bounds__(128) void k_stage1(LevelPtrs lp, float* scores,
                                                int* cls_out, float4* boxes) {
    int q = blockIdx.x * 128 + threadIdx.x;
    int b = blockIdx.y;
    if (q >= NQUAD) return;

    int lvl, qoff, logw, strd;
    if (q < 4096)      { lvl = 0; qoff = 0;    logw = 7; strd = 8;   }
    else if (q < 5120) { lvl = 1; qoff = 4096; logw = 6; strd = 16;  }
    else if (q < 5376) { lvl = 2; qoff = 5120; logw = 5; strd = 32;  }
    else if (q < 5440) { lvl = 3; qoff = 5376; logw = 4; strd = 64;  }
    else               { lvl = 4; qoff = 5440; logw = 3; strd = 128; }

    int loc = (q - qoff) * 4;           // level-LOCAL index; 4 consecutive, same row
    int hw  = 1 << (2 * logw);
    int hw4 = hw >> 2;
    int x   = loc & ((1 << logw) - 1);
    int y   = loc >> logw;

    const float4* cp = (const float4*)(lp.cls[lvl] + (size_t)(b * NCLS) * hw + loc);

    float4 l0v = cp[0];
    const float* l0 = (const float*)&l0v;
    float eb[4], bs[4];
    int   bc[4];
#pragma unroll
    for (int u = 0; u < 4; ++u) {
        eb[u] = expf(-l0[u]);
        bs[u] = 1.0f / (1.0f + eb[u]);
        bc[u] = 0;
    }
    for (int c = 1; c < NCLS; ++c) {
        float4 lv = cp[(size_t)c * hw4];
        const float* lf = (const float*)&lv;
#pragma unroll
        for (int u = 0; u < 4; ++u) {
            float e = expf(-lf[u]);
            if (e < eb[u]) {            // sigmoid monotone: only then can it beat best
                float sg = 1.0f / (1.0f + e);
                if (sg > bs[u]) { bs[u] = sg; bc[u] = c; }
                eb[u] = e;
            }
        }
    }

    float4 lcv = *(const float4*)(lp.cnt[lvl] + (size_t)b * hw + loc);
    const float* lc = (const float*)&lcv;

    const float4* rp = (const float4*)(lp.reg[lvl] + (size_t)(b * 4) * hw + loc);
    float4 r0v = rp[0], r1v = rp[hw4], r2v = rp[2 * hw4], r3v = rp[3 * hw4];
    const float* r0 = (const float*)&r0v;
    const float* r1 = (const float*)&r1v;
    const float* r2 = (const float*)&r2v;
    const float* r3 = (const float*)&r3v;

    float cy = (float)(y * strd + (strd >> 1));

    float sc4[4]; int cl4[4]; float4 bx4[4];
#pragma unroll
    for (int u = 0; u < 4; ++u) {
        float sig_cnt = 1.0f / (1.0f + expf(-lc[u]));
        sc4[u] = sqrtf(__fmul_rn(bs[u], sig_cnt));
        cl4[u] = bc[u] + 1;
        float cx = (float)((x + u) * strd + (strd >> 1));
        bx4[u] = make_float4(__fsub_rn(cx, r0[u]), __fsub_rn(cy, r1[u]),
                             __fadd_rn(cx, r2[u]), __fadd_rn(cy, r3[u]));
    }

    // GLOBAL output index: level offset + local loc == q*4  (R2 bug was b*NLOC+loc)
    int o = b * NLOC + q * 4;
    *(float4*)(scores + o) = make_float4(sc4[0], sc4[1], sc4[2], sc4[3]);
    *(int4*)(cls_out + o)  = make_int4(cl4[0], cl4[1], cl4[2], cl4[3]);
#pragma unroll
    for (int u = 0; u < 4; ++u) boxes[o + u] = bx4[u];
}

// ---------------------------------------------------------------------------
// K2: per-batch exact top-1000 (stable desc by (score, -idx)) via radix-select
//     1024 threads, uint4 loads, parallel suffix-sum digit select
// ---------------------------------------------------------------------------
__global__ __launch_bounds__(1024) void k_select(const uint32_t* scores_u,
                                                 float* topk_score, int* topk_idx) {
    __shared__ uint32_t hist[256];
    __shared__ uint32_t cum[256];
    __shared__ uint64_t keys[2048];
    __shared__ uint32_t prefix_sh, cnt_sh;
    __shared__ int R_sh;

    int b = blockIdx.x, tid = threadIdx.x;
    const uint4* sc4 = (const uint4*)(scores_u + (size_t)b * NLOC);

    uint32_t prefix = 0;
    int R = MAXDET;
    for (int d = 3; d >= 0; --d) {
        if (tid < 256) hist[tid] = 0;
        __syncthreads();
        int shl = 8 * d;
        int last = -1; uint32_t run = 0;
        for (int n4 = tid; n4 < NQUAD; n4 += 1024) {
            uint4 v = sc4[n4];
            uint32_t vals[4] = {v.x, v.y, v.z, v.w};
#pragma unroll
            for (int u = 0; u < 4; ++u) {
                uint32_t sb = vals[u];
                bool m = (d == 3) || ((sb >> (shl + 8)) == prefix);
                int dig = m ? (int)((sb >> shl) & 255u) : -1;
                if (dig != last) {
                    if (last >= 0 && run) atomicAdd(&hist[last], run);
                    last = dig; run = 0;
                }
                if (dig >= 0) run++;
            }
        }
        if (last >= 0 && run) atomicAdd(&hist[last], run);
        __syncthreads();

        // parallel suffix sum over 256 bins: cum[d] = sum_{d'>=d} hist[d']
        if (tid < 256) cum[tid] = hist[tid];
        __syncthreads();
        for (int st = 1; st < 256; st <<= 1) {
            uint32_t v = 0;
            if (tid < 256) v = cum[tid] + ((tid + st < 256) ? cum[tid + st] : 0);
            __syncthreads();
            if (tid < 256) cum[tid] = v;
            __syncthreads();
        }
        if (tid < 256) {
            uint32_t cge  = cum[tid];
            uint32_t cge1 = (tid < 255) ? cum[tid + 1] : 0;
            if (cge >= (uint32_t)R && cge1 < (uint32_t)R) {
                prefix_sh = (prefix << 8) | (uint32_t)tid;
                R_sh = R - (int)cge1;
            }
        }
        __syncthreads();
        prefix = prefix_sh;
        R = R_sh;
        __syncthreads();
    }
    uint32_t Sstar = prefix;

    if (tid == 0) cnt_sh = 0;
    __syncthreads();
    for (int n4 = tid; n4 < NQUAD; n4 += 1024) {
        uint4 v = sc4[n4];
        uint32_t vals[4] = {v.x, v.y, v.z, v.w};
#pragma unroll
        for (int u = 0; u < 4; ++u) {
            uint32_t sb = vals[u];
            if (sb >= Sstar) {
                uint32_t n = (uint32_t)(n4 * 4 + u);
                uint32_t slot = atomicAdd(&cnt_sh, 1u);
                if (slot < 2048)
                    keys[slot] = ((uint64_t)sb << 32) | (uint32_t)(~n);
            }
        }
    }
    __syncthreads();
    uint32_t cnt = cnt_sh > 2048u ? 2048u : cnt_sh;
    for (int i = tid; i < 2048; i += 1024)
        if (i >= (int)cnt) keys[i] = 0;
    __syncthreads();

    // bitonic sort, descending — 1 pair per thread per phase
    for (int k = 2; k <= 2048; k <<= 1) {
        for (int j = k >> 1; j > 0; j >>= 1) {
            for (int i = tid; i < 2048; i += 1024) {
                int l = i ^ j;
                if (l > i) {
                    uint64_t a = keys[i], c = keys[l];
                    bool desc = ((i & k) == 0);
                    if (desc ? (a < c) : (a > c)) { keys[i] = c; keys[l] = a; }
                }
            }
            __syncthreads();
        }
    }
    for (int r = tid; r < MAXDET; r += 1024) {
        uint64_t key = keys[r];
        topk_score[b * MAXDET + r] = __uint_as_float((uint32_t)(key >> 32));
        topk_idx[b * MAXDET + r]   = (int)(~(uint32_t)key);
    }
}

// ---------------------------------------------------------------------------
// K3: gather topk, per-batch maxc, class-offset boxes + areas
// ---------------------------------------------------------------------------
__global__ __launch_bounds__(256) void k_prep(const float4* boxes, const int* cls_ws,
                                              const int* topk_idx, float4* gbox,
                                              int* gcls, float4* obox, float* areas) {
    __shared__ float red[256];
    int b = blockIdx.x, tid = threadIdx.x;

    float4 bx[4]; int cls4[4];
    float m = -3.0e38f;
    for (int q = 0; q < 4; ++q) {
        int r = tid + q * 256;
        if (r < MAXDET) {
            int idx = topk_idx[b * MAXDET + r];
            float4 v = boxes[(size_t)b * NLOC + idx];
            bx[q] = v;
            cls4[q] = cls_ws[(size_t)b * NLOC + idx];
            m = fmaxf(m, fmaxf(fmaxf(v.x, v.y), fmaxf(v.z, v.w)));
        }
    }
    red[tid] = m;
    __syncthreads();
    for (int s = 128; s > 0; s >>= 1) {
        if (tid < s) red[tid] = fmaxf(red[tid], red[tid + s]);
        __syncthreads();
    }
    float maxc1 = __fadd_rn(red[0], 1.0f);

    for (int q = 0; q < 4; ++q) {
        int r = tid + q * 256;
        if (r < MAXDET) {
            float off = __fmul_rn((float)cls4[q], maxc1);
            float4 v = bx[q];
            float4 o = make_float4(__fadd_rn(v.x, off), __fadd_rn(v.y, off),
                                   __fadd_rn(v.z, off), __fadd_rn(v.w, off));
            obox[b * MAXDET + r] = o;
            areas[b * MAXDET + r] =
                __fmul_rn(__fadd_rn(__fsub_rn(o.z, o.x), 1.0f),
                          __fadd_rn(__fsub_rn(o.w, o.y), 1.0f));
            gbox[b * MAXDET + r] = v;
            gcls[b * MAXDET + r] = cls4[q];
        }
    }
}

// ---------------------------------------------------------------------------
// K4: suppression bit-matrix rows (j > i); thread t handles rows t and 999-t
//     so every thread does ~999 inner iterations (balanced triangle)
// ---------------------------------------------------------------------------
__global__ __launch_bounds__(256) void k_iou(const float4* obox, const float* areas,
                                             uint64_t* rows) {
    __shared__ float4 ob[MAXDET];
    __shared__ float  ar[MAXDET];
    int b = blockIdx.x, tid = threadIdx.x;
    for (int r = tid; r < MAXDET; r += 256) {
        ob[r] = obox[b * MAXDET + r];
        ar[r] = areas[b * MAXDET + r];
    }
    __syncthreads();
    int t = blockIdx.y * 256 + tid;   // t in [0,512); pairs (t, 999-t) for t<500
    if (t >= 500) return;

#pragma unroll
    for (int half = 0; half < 2; ++half) {
        int i = half ? (MAXDET - 1 - t) : t;
        float4 bi = ob[i];
        float ai = ar[i];
        uint64_t row[16];
#pragma unroll
        for (int w = 0; w < 16; ++w) row[w] = 0;
        for (int j = i + 1; j < MAXDET; ++j) {
            float4 bj = ob[j];
            float xx1 = fmaxf(bi.x, bj.x), yy1 = fmaxf(bi.y, bj.y);
            float xx2 = fminf(bi.z, bj.z), yy2 = fminf(bi.w, bj.w);
            float w_ = fmaxf(__fsub_rn(xx2, xx1), 0.0f);
            float h_ = fmaxf(__fsub_rn(yy2, yy1), 0.0f);
            float inter = __fmul_rn(w_, h_);
            float denom = __fsub_rn(__fadd_rn(ai, ar[j]), inter);
            if (inter > __fmul_rn(0.6f, denom)) row[j >> 6] |= (1ull << (j & 63));
        }
        uint64_t* rp = rows + ((size_t)(b * MAXDET) + i) * 16;
#pragma unroll
        for (int w = 0; w < 16; ++w) rp[w] = row[w];
    }
}

// ---------------------------------------------------------------------------
// K5: sequential greedy scan (wave 0, 16 mask lanes), unroll-4 row prefetch
// ---------------------------------------------------------------------------
__global__ __launch_bounds__(256) void k_nms_out(const uint64_t* rows,
                                                 const float* topk_score,
                                                 const int* gcls, const float4* gbox,
                                                 float* out) {
    __shared__ __align__(16) uint64_t rows_lds[8000];   // 500 rows x 16 words
    __shared__ uint64_t validmask[16];
    __shared__ uint64_t keepmask[16];
    int b = blockIdx.x, tid = threadIdx.x;

    if (tid < 16) validmask[tid] = 0;
    __syncthreads();
    for (int r = tid; r < MAXDET; r += 256)
        if (topk_score[b * MAXDET + r] >= 0.05f)
            atomicOr(&validmask[r >> 6], 1ull << (r & 63));
    __syncthreads();

    uint64_t S_reg = 0, K_reg = 0, V_reg = 0;
    if (tid < 16) V_reg = validmask[tid];

    for (int p = 0; p < 2; ++p) {
        const ulonglong2* rg =
            (const ulonglong2*)(rows + ((size_t)(b * MAXDET) + p * 500) * 16);
        for (int w = tid; w < 4000; w += 256)
            ((ulonglong2*)rows_lds)[w] = rg[w];
        __syncthreads();
        if (tid < 64) {
            for (int ii0 = 0; ii0 < 500; ii0 += 4) {
                uint64_t rw[4];
#pragma unroll
                for (int u = 0; u < 4; ++u)
                    rw[u] = (tid < 16) ? rows_lds[(ii0 + u) * 16 + tid] : 0ull;
#pragma unroll
                for (int u = 0; u < 4; ++u) {
                    int gi = p * 500 + ii0 + u;
                    int word = gi >> 6, bitp = gi & 63;
                    uint64_t sw = shfl64(S_reg, word);
                    uint64_t vw = shfl64(V_reg, word);
                    bool alive = (((vw >> bitp) & 1ull) != 0) &&
                                 (((sw >> bitp) & 1ull) == 0);
                    S_reg |= alive ? rw[u] : 0ull;
                    if (alive && tid == word) K_reg |= (1ull << bitp);
                }
            }
        }
        __syncthreads();
    }
    if (tid < 16) keepmask[tid] = K_reg;
    __syncthreads();

    for (int r = tid; r < MAXDET; r += 256) {
        bool keep = ((keepmask[r >> 6] >> (r & 63)) & 1ull) != 0;
        float sc = topk_score[b * MAXDET + r];
        int cl = gcls[b * MAXDET + r];
        float4 v = gbox[b * MAXDET + r];
        float c0 = fminf(fmaxf(v.x, 0.0f), 1023.0f);
        float c1 = fminf(fmaxf(v.y, 0.0f), 1023.0f);
        float c2 = fminf(fmaxf(v.z, 0.0f), 1023.0f);
        float c3 = fminf(fmaxf(v.w, 0.0f), 1023.0f);
        out[b * MAXDET + r] = keep ? sc : 0.0f;
        out[BATCH * MAXDET + b * MAXDET + r] = keep ? (float)cl : 0.0f;
        float4* op = (float4*)(out + 2 * BATCH * MAXDET) + (b * MAXDET + r);
        *op = keep ? make_float4(c0, c1, c2, c3) : make_float4(0.f, 0.f, 0.f, 0.f);
    }
}

// ---------------------------------------------------------------------------
extern "C" void kernel_launch(void* const* d_in, const int* in_sizes, int n_in,
                              void* d_out, int out_size, void* d_ws, size_t ws_size,
                              hipStream_t stream) {
    (void)in_sizes; (void)n_in; (void)out_size; (void)ws_size;

    LevelPtrs lp;
    for (int i = 0; i < 5; ++i) {
        lp.cls[i] = (const float*)d_in[3 * i + 0];
        lp.cnt[i] = (const float*)d_in[3 * i + 1];
        lp.reg[i] = (const float*)d_in[3 * i + 2];
    }

    char* ws = (char*)d_ws;
    float*    scores   = (float*)   (ws + 0);          // 8*21824*4   = 698368
    int*      cls_ws   = (int*)     (ws + 698368);     // 698368
    float4*   boxes    = (float4*)  (ws + 1396736);    // 8*21824*16  = 2793472
    int*      topk_idx = (int*)     (ws + 4190208);    // 32000
    float*    topk_sc  = (float*)   (ws + 4222208);    // 32000
    int*      gcls     = (int*)     (ws + 4254208);    // 32000
    float4*   gbox     = (float4*)  (ws + 4286208);    // 128000
    float4*   obox     = (float4*)  (ws + 4414208);    // 128000
    float*    areas    = (float*)   (ws + 4542208);    // 32000
    uint64_t* rows     = (uint64_t*)(ws + 4574208);    // 8*1000*16*8 = 1024000

    dim3 g1((NQUAD + 127) / 128, BATCH);
    k_stage1<<<g1, 128, 0, stream>>>(lp, scores, cls_ws, boxes);

    k_select<<<BATCH, 1024, 0, stream>>>((const uint32_t*)scores, topk_sc, topk_idx);

    k_prep<<<BATCH, 256, 0, stream>>>(boxes, cls_ws, topk_idx, gbox, gcls, obox, areas);

    dim3 g4(BATCH, 2);
    k_iou<<<g4, 256, 0, stream>>>(obox, areas, rows);

    k_nms_out<<<BATCH, 256, 0, stream>>>(rows, topk_sc, gcls, gbox, (float*)d_out);
}

// Round 4
// 403.681 us; speedup vs baseline: 1.7552x; 1.2522x over previous
//
#include <hip/hip_runtime.h>
#include <stdint.h>

#define NLOC   21824
#define NQUAD  5456          // NLOC/4
#define BATCH  8
#define MAXDET 1000
#define NCLS   80

struct LevelPtrs {
    const float* cls[5];
    const float* cnt[5];
    const float* reg[5];
};

__device__ inline uint64_t shfl64(uint64_t v, int lane) {
    int lo = __shfl((int)(uint32_t)(v & 0xffffffffull), lane, 64);
    int hi = __shfl((int)(uint32_t)(v >> 32), lane, 64);
    return ((uint64_t)(uint32_t)hi << 32) | (uint32_t)(uint32_t)lo;
}

// ---------------------------------------------------------------------------
// K1: per-location score / class / box — 4 locations per thread, float4 loads
// ---------------------------------------------------------------------------
__global__ __launch_bounds__(128) void k_stage1(LevelPtrs lp, float* scores,
                                                int* cls_out, float4* boxes) {
    int q = blockIdx.x * 128 + threadIdx.x;
    int b = blockIdx.y;
    if (q >= NQUAD) return;

    int lvl, qoff, logw, strd;
    if (q < 4096)      { lvl = 0; qoff = 0;    logw = 7; strd = 8;   }
    else if (q < 5120) { lvl = 1; qoff = 4096; logw = 6; strd = 16;  }
    else if (q < 5376) { lvl = 2; qoff = 5120; logw = 5; strd = 32;  }
    else if (q < 5440) { lvl = 3; qoff = 5376; logw = 4; strd = 64;  }
    else               { lvl = 4; qoff = 5440; logw = 3; strd = 128; }

    int loc = (q - qoff) * 4;           // level-LOCAL index; 4 consecutive, same row
    int hw  = 1 << (2 * logw);
    int hw4 = hw >> 2;
    int x   = loc & ((1 << logw) - 1);
    int y   = loc >> logw;

    const float4* cp = (const float4*)(lp.cls[lvl] + (size_t)(b * NCLS) * hw + loc);

    float4 l0v = cp[0];
    const float* l0 = (const float*)&l0v;
    float eb[4], bs[4];
    int   bc[4];
#pragma unroll
    for (int u = 0; u < 4; ++u) {
        eb[u] = expf(-l0[u]);
        bs[u] = 1.0f / (1.0f + eb[u]);
        bc[u] = 0;
    }
    for (int c = 1; c < NCLS; ++c) {
        float4 lv = cp[(size_t)c * hw4];
        const float* lf = (const float*)&lv;
#pragma unroll
        for (int u = 0; u < 4; ++u) {
            float e = expf(-lf[u]);
            if (e < eb[u]) {            // sigmoid monotone: only then can it beat best
                float sg = 1.0f / (1.0f + e);
                if (sg > bs[u]) { bs[u] = sg; bc[u] = c; }
                eb[u] = e;
            }
        }
    }

    float4 lcv = *(const float4*)(lp.cnt[lvl] + (size_t)b * hw + loc);
    const float* lc = (const float*)&lcv;

    const float4* rp = (const float4*)(lp.reg[lvl] + (size_t)(b * 4) * hw + loc);
    float4 r0v = rp[0], r1v = rp[hw4], r2v = rp[2 * hw4], r3v = rp[3 * hw4];
    const float* r0 = (const float*)&r0v;
    const float* r1 = (const float*)&r1v;
    const float* r2 = (const float*)&r2v;
    const float* r3 = (const float*)&r3v;

    float cy = (float)(y * strd + (strd >> 1));

    float sc4[4]; int cl4[4]; float4 bx4[4];
#pragma unroll
    for (int u = 0; u < 4; ++u) {
        float sig_cnt = 1.0f / (1.0f + expf(-lc[u]));
        sc4[u] = sqrtf(__fmul_rn(bs[u], sig_cnt));
        cl4[u] = bc[u] + 1;
        float cx = (float)((x + u) * strd + (strd >> 1));
        bx4[u] = make_float4(__fsub_rn(cx, r0[u]), __fsub_rn(cy, r1[u]),
                             __fadd_rn(cx, r2[u]), __fadd_rn(cy, r3[u]));
    }

    int o = b * NLOC + q * 4;   // global index = level offset + local loc
    *(float4*)(scores + o) = make_float4(sc4[0], sc4[1], sc4[2], sc4[3]);
    *(int4*)(cls_out + o)  = make_int4(cl4[0], cl4[1], cl4[2], cl4[3]);
#pragma unroll
    for (int u = 0; u < 4; ++u) boxes[o + u] = bx4[u];
}

// ---------------------------------------------------------------------------
// K2: per-batch exact top-1000 (stable desc by (score, -idx)) via radix-select
// ---------------------------------------------------------------------------
__global__ __launch_bounds__(1024) void k_select(const uint32_t* scores_u,
                                                 float* topk_score, int* topk_idx) {
    __shared__ uint32_t hist[256];
    __shared__ uint32_t cum[256];
    __shared__ uint64_t keys[2048];
    __shared__ uint32_t prefix_sh, cnt_sh;
    __shared__ int R_sh;

    int b = blockIdx.x, tid = threadIdx.x;
    const uint4* sc4 = (const uint4*)(scores_u + (size_t)b * NLOC);

    uint32_t prefix = 0;
    int R = MAXDET;
    for (int d = 3; d >= 0; --d) {
        if (tid < 256) hist[tid] = 0;
        __syncthreads();
        int shl = 8 * d;
        int last = -1; uint32_t run = 0;
        for (int n4 = tid; n4 < NQUAD; n4 += 1024) {
            uint4 v = sc4[n4];
            uint32_t vals[4] = {v.x, v.y, v.z, v.w};
#pragma unroll
            for (int u = 0; u < 4; ++u) {
                uint32_t sb = vals[u];
                bool m = (d == 3) || ((sb >> (shl + 8)) == prefix);
                int dig = m ? (int)((sb >> shl) & 255u) : -1;
                if (dig != last) {
                    if (last >= 0 && run) atomicAdd(&hist[last], run);
                    last = dig; run = 0;
                }
                if (dig >= 0) run++;
            }
        }
        if (last >= 0 && run) atomicAdd(&hist[last], run);
        __syncthreads();

        // parallel suffix sum over 256 bins
        if (tid < 256) cum[tid] = hist[tid];
        __syncthreads();
        for (int st = 1; st < 256; st <<= 1) {
            uint32_t v = 0;
            if (tid < 256) v = cum[tid] + ((tid + st < 256) ? cum[tid + st] : 0);
            __syncthreads();
            if (tid < 256) cum[tid] = v;
            __syncthreads();
        }
        if (tid < 256) {
            uint32_t cge  = cum[tid];
            uint32_t cge1 = (tid < 255) ? cum[tid + 1] : 0;
            if (cge >= (uint32_t)R && cge1 < (uint32_t)R) {
                prefix_sh = (prefix << 8) | (uint32_t)tid;
                R_sh = R - (int)cge1;
            }
        }
        __syncthreads();
        prefix = prefix_sh;
        R = R_sh;
        __syncthreads();
    }
    uint32_t Sstar = prefix;

    if (tid == 0) cnt_sh = 0;
    __syncthreads();
    for (int n4 = tid; n4 < NQUAD; n4 += 1024) {
        uint4 v = sc4[n4];
        uint32_t vals[4] = {v.x, v.y, v.z, v.w};
#pragma unroll
        for (int u = 0; u < 4; ++u) {
            uint32_t sb = vals[u];
            if (sb >= Sstar) {
                uint32_t n = (uint32_t)(n4 * 4 + u);
                uint32_t slot = atomicAdd(&cnt_sh, 1u);
                if (slot < 2048)
                    keys[slot] = ((uint64_t)sb << 32) | (uint32_t)(~n);
            }
        }
    }
    __syncthreads();
    uint32_t cnt = cnt_sh > 2048u ? 2048u : cnt_sh;
    for (int i = tid; i < 2048; i += 1024)
        if (i >= (int)cnt) keys[i] = 0;
    __syncthreads();

    for (int k = 2; k <= 2048; k <<= 1) {
        for (int j = k >> 1; j > 0; j >>= 1) {
            for (int i = tid; i < 2048; i += 1024) {
                int l = i ^ j;
                if (l > i) {
                    uint64_t a = keys[i], c = keys[l];
                    bool desc = ((i & k) == 0);
                    if (desc ? (a < c) : (a > c)) { keys[i] = c; keys[l] = a; }
                }
            }
            __syncthreads();
        }
    }
    for (int r = tid; r < MAXDET; r += 1024) {
        uint64_t key = keys[r];
        topk_score[b * MAXDET + r] = __uint_as_float((uint32_t)(key >> 32));
        topk_idx[b * MAXDET + r]   = (int)(~(uint32_t)key);
    }
}

// ---------------------------------------------------------------------------
// K3: gather topk, per-batch maxc, class-offset boxes + areas
// ---------------------------------------------------------------------------
__global__ __launch_bounds__(256) void k_prep(const float4* boxes, const int* cls_ws,
                                              const int* topk_idx, float4* gbox,
                                              int* gcls, float4* obox, float* areas) {
    __shared__ float red[256];
    int b = blockIdx.x, tid = threadIdx.x;

    float4 bx[4]; int cls4[4];
    float m = -3.0e38f;
    for (int q = 0; q < 4; ++q) {
        int r = tid + q * 256;
        if (r < MAXDET) {
            int idx = topk_idx[b * MAXDET + r];
            float4 v = boxes[(size_t)b * NLOC + idx];
            bx[q] = v;
            cls4[q] = cls_ws[(size_t)b * NLOC + idx];
            m = fmaxf(m, fmaxf(fmaxf(v.x, v.y), fmaxf(v.z, v.w)));
        }
    }
    red[tid] = m;
    __syncthreads();
    for (int s = 128; s > 0; s >>= 1) {
        if (tid < s) red[tid] = fmaxf(red[tid], red[tid + s]);
        __syncthreads();
    }
    float maxc1 = __fadd_rn(red[0], 1.0f);

    for (int q = 0; q < 4; ++q) {
        int r = tid + q * 256;
        if (r < MAXDET) {
            float off = __fmul_rn((float)cls4[q], maxc1);
            float4 v = bx[q];
            float4 o = make_float4(__fadd_rn(v.x, off), __fadd_rn(v.y, off),
                                   __fadd_rn(v.z, off), __fadd_rn(v.w, off));
            obox[b * MAXDET + r] = o;
            areas[b * MAXDET + r] =
                __fmul_rn(__fadd_rn(__fsub_rn(o.z, o.x), 1.0f),
                          __fadd_rn(__fsub_rn(o.w, o.y), 1.0f));
            gbox[b * MAXDET + r] = v;
            gcls[b * MAXDET + r] = cls4[q];
        }
    }
}

// ---------------------------------------------------------------------------
// K4: suppression bits — one thread computes one (row i, 64-col word) uint64.
// Grid (BATCH, 16 words) x 256 threads, 4 rows/thread. Column boxes in LDS,
// read as wave-broadcast (all lanes same j). Every (i,word) slot is stored
// (rows buffer is poisoned, zero-words must be written).
// ---------------------------------------------------------------------------
__global__ __launch_bounds__(256) void k_iou(const float4* obox, const float* areas,
                                             uint64_t* rows) {
    __shared__ float4 cb[64];
    __shared__ float  ca[64];
    int b = blockIdx.x, word = blockIdx.y, tid = threadIdx.x;
    int j0 = word * 64;
    int jlim = MAXDET - j0;              // valid columns in this word
    if (jlim > 64) jlim = 64;

    if (tid < 64 && tid < jlim) {
        cb[tid] = obox[b * MAXDET + j0 + tid];
        ca[tid] = areas[b * MAXDET + j0 + tid];
    }
    __syncthreads();

#pragma unroll
    for (int qr = 0; qr < 4; ++qr) {
        int i = tid + qr * 256;
        if (i >= MAXDET) continue;
        uint64_t rw = 0;
        int jmax = j0 + jlim;            // one past last valid j
        if (i < jmax - 1) {              // any j in word with j > i ?
            float4 bi = obox[b * MAXDET + i];
            float ai = areas[b * MAXDET + i];
            for (int jj = 0; jj < jlim; ++jj) {
                int j = j0 + jj;
                float4 bj = cb[jj];
                float xx1 = fmaxf(bi.x, bj.x), yy1 = fmaxf(bi.y, bj.y);
                float xx2 = fminf(bi.z, bj.z), yy2 = fminf(bi.w, bj.w);
                float w_ = fmaxf(__fsub_rn(xx2, xx1), 0.0f);
                float h_ = fmaxf(__fsub_rn(yy2, yy1), 0.0f);
                float inter = __fmul_rn(w_, h_);
                float denom = __fsub_rn(__fadd_rn(ai, ca[jj]), inter);
                bool sup = (j > i) && (inter > __fmul_rn(0.6f, denom));
                rw |= sup ? (1ull << jj) : 0ull;
            }
        }
        rows[((size_t)(b * MAXDET) + i) * 16 + word] = rw;
    }
}

// ---------------------------------------------------------------------------
// K5: sequential greedy scan (wave 0, 16 mask lanes), unroll-4 row prefetch
// ---------------------------------------------------------------------------
__global__ __launch_bounds__(256) void k_nms_out(const uint64_t* rows,
                                                 const float* topk_score,
                                                 const int* gcls, const float4* gbox,
                                                 float* out) {
    __shared__ __align__(16) uint64_t rows_lds[8000];   // 500 rows x 16 words
    __shared__ uint64_t validmask[16];
    __shared__ uint64_t keepmask[16];
    int b = blockIdx.x, tid = threadIdx.x;

    if (tid < 16) validmask[tid] = 0;
    __syncthreads();
    for (int r = tid; r < MAXDET; r += 256)
        if (topk_score[b * MAXDET + r] >= 0.05f)
            atomicOr(&validmask[r >> 6], 1ull << (r & 63));
    __syncthreads();

    uint64_t S_reg = 0, K_reg = 0, V_reg = 0;
    if (tid < 16) V_reg = validmask[tid];

    for (int p = 0; p < 2; ++p) {
        const ulonglong2* rg =
            (const ulonglong2*)(rows + ((size_t)(b * MAXDET) + p * 500) * 16);
        for (int w = tid; w < 4000; w += 256)
            ((ulonglong2*)rows_lds)[w] = rg[w];
        __syncthreads();
        if (tid < 64) {
            for (int ii0 = 0; ii0 < 500; ii0 += 4) {
                uint64_t rw[4];
#pragma unroll
                for (int u = 0; u < 4; ++u)
                    rw[u] = (tid < 16) ? rows_lds[(ii0 + u) * 16 + tid] : 0ull;
#pragma unroll
                for (int u = 0; u < 4; ++u) {
                    int gi = p * 500 + ii0 + u;
                    int word = gi >> 6, bitp = gi & 63;
                    uint64_t sw = shfl64(S_reg, word);
                    uint64_t vw = shfl64(V_reg, word);
                    bool alive = (((vw >> bitp) & 1ull) != 0) &&
                                 (((sw >> bitp) & 1ull) == 0);
                    S_reg |= alive ? rw[u] : 0ull;
                    if (alive && tid == word) K_reg |= (1ull << bitp);
                }
            }
        }
        __syncthreads();
    }
    if (tid < 16) keepmask[tid] = K_reg;
    __syncthreads();

    for (int r = tid; r < MAXDET; r += 256) {
        bool keep = ((keepmask[r >> 6] >> (r & 63)) & 1ull) != 0;
        float sc = topk_score[b * MAXDET + r];
        int cl = gcls[b * MAXDET + r];
        float4 v = gbox[b * MAXDET + r];
        float c0 = fminf(fmaxf(v.x, 0.0f), 1023.0f);
        float c1 = fminf(fmaxf(v.y, 0.0f), 1023.0f);
        float c2 = fminf(fmaxf(v.z, 0.0f), 1023.0f);
        float c3 = fminf(fmaxf(v.w, 0.0f), 1023.0f);
        out[b * MAXDET + r] = keep ? sc : 0.0f;
        out[BATCH * MAXDET + b * MAXDET + r] = keep ? (float)cl : 0.0f;
        float4* op = (float4*)(out + 2 * BATCH * MAXDET) + (b * MAXDET + r);
        *op = keep ? make_float4(c0, c1, c2, c3) : make_float4(0.f, 0.f, 0.f, 0.f);
    }
}

// ---------------------------------------------------------------------------
extern "C" void kernel_launch(void* const* d_in, const int* in_sizes, int n_in,
                              void* d_out, int out_size, void* d_ws, size_t ws_size,
                              hipStream_t stream) {
    (void)in_sizes; (void)n_in; (void)out_size; (void)ws_size;

    LevelPtrs lp;
    for (int i = 0; i < 5; ++i) {
        lp.cls[i] = (const float*)d_in[3 * i + 0];
        lp.cnt[i] = (const float*)d_in[3 * i + 1];
        lp.reg[i] = (const float*)d_in[3 * i + 2];
    }

    char* ws = (char*)d_ws;
    float*    scores   = (float*)   (ws + 0);          // 8*21824*4   = 698368
    int*      cls_ws   = (int*)     (ws + 698368);     // 698368
    float4*   boxes    = (float4*)  (ws + 1396736);    // 8*21824*16  = 2793472
    int*      topk_idx = (int*)     (ws + 4190208);    // 32000
    float*    topk_sc  = (float*)   (ws + 4222208);    // 32000
    int*      gcls     = (int*)     (ws + 4254208);    // 32000
    float4*   gbox     = (float4*)  (ws + 4286208);    // 128000
    float4*   obox     = (float4*)  (ws + 4414208);    // 128000
    float*    areas    = (float*)   (ws + 4542208);    // 32000
    uint64_t* rows     = (uint64_t*)(ws + 4574208);    // 8*1000*16*8 = 1024000

    dim3 g1((NQUAD + 127) / 128, BATCH);
    k_stage1<<<g1, 128, 0, stream>>>(lp, scores, cls_ws, boxes);

    k_select<<<BATCH, 1024, 0, stream>>>((const uint32_t*)scores, topk_sc, topk_idx);

    k_prep<<<BATCH, 256, 0, stream>>>(boxes, cls_ws, topk_idx, gbox, gcls, obox, areas);

    dim3 g4(BATCH, 16);
    k_iou<<<g4, 256, 0, stream>>>(obox, areas, rows);

    k_nms_out<<<BATCH, 256, 0, stream>>>(rows, topk_sc, gcls, gbox, (float*)d_out);
}

// Round 5
// 389.595 us; speedup vs baseline: 1.8186x; 1.0362x over previous
//
#include <hip/hip_runtime.h>
#include <stdint.h>

#define NLOC   21824
#define NQUAD  5456          // NLOC/4
#define BATCH  8
#define MAXDET 1000
#define NCLS   80

struct LevelPtrs {
    const float* cls[5];
    const float* cnt[5];
    const float* reg[5];
};

// ---------------------------------------------------------------------------
// K1: per-location score / class / box — 4 locations per thread, float4 loads
// ---------------------------------------------------------------------------
__global__ __launch_bounds__(128) void k_stage1(LevelPtrs lp, float* scores,
                                                int* cls_out, float4* boxes) {
    int q = blockIdx.x * 128 + threadIdx.x;
    int b = blockIdx.y;
    if (q >= NQUAD) return;

    int lvl, qoff, logw, strd;
    if (q < 4096)      { lvl = 0; qoff = 0;    logw = 7; strd = 8;   }
    else if (q < 5120) { lvl = 1; qoff = 4096; logw = 6; strd = 16;  }
    else if (q < 5376) { lvl = 2; qoff = 5120; logw = 5; strd = 32;  }
    else if (q < 5440) { lvl = 3; qoff = 5376; logw = 4; strd = 64;  }
    else               { lvl = 4; qoff = 5440; logw = 3; strd = 128; }

    int loc = (q - qoff) * 4;           // level-LOCAL index; 4 consecutive, same row
    int hw  = 1 << (2 * logw);
    int hw4 = hw >> 2;
    int x   = loc & ((1 << logw) - 1);
    int y   = loc >> logw;

    const float4* cp = (const float4*)(lp.cls[lvl] + (size_t)(b * NCLS) * hw + loc);

    float4 l0v = cp[0];
    const float* l0 = (const float*)&l0v;
    float eb[4], bs[4];
    int   bc[4];
#pragma unroll
    for (int u = 0; u < 4; ++u) {
        eb[u] = expf(-l0[u]);
        bs[u] = 1.0f / (1.0f + eb[u]);
        bc[u] = 0;
    }
    for (int c = 1; c < NCLS; ++c) {
        float4 lv = cp[(size_t)c * hw4];
        const float* lf = (const float*)&lv;
#pragma unroll
        for (int u = 0; u < 4; ++u) {
            float e = expf(-lf[u]);
            if (e < eb[u]) {            // sigmoid monotone: only then can it beat best
                float sg = 1.0f / (1.0f + e);
                if (sg > bs[u]) { bs[u] = sg; bc[u] = c; }
                eb[u] = e;
            }
        }
    }

    float4 lcv = *(const float4*)(lp.cnt[lvl] + (size_t)b * hw + loc);
    const float* lc = (const float*)&lcv;

    const float4* rp = (const float4*)(lp.reg[lvl] + (size_t)(b * 4) * hw + loc);
    float4 r0v = rp[0], r1v = rp[hw4], r2v = rp[2 * hw4], r3v = rp[3 * hw4];
    const float* r0 = (const float*)&r0v;
    const float* r1 = (const float*)&r1v;
    const float* r2 = (const float*)&r2v;
    const float* r3 = (const float*)&r3v;

    float cy = (float)(y * strd + (strd >> 1));

    float sc4[4]; int cl4[4]; float4 bx4[4];
#pragma unroll
    for (int u = 0; u < 4; ++u) {
        float sig_cnt = 1.0f / (1.0f + expf(-lc[u]));
        sc4[u] = sqrtf(__fmul_rn(bs[u], sig_cnt));
        cl4[u] = bc[u] + 1;
        float cx = (float)((x + u) * strd + (strd >> 1));
        bx4[u] = make_float4(__fsub_rn(cx, r0[u]), __fsub_rn(cy, r1[u]),
                             __fadd_rn(cx, r2[u]), __fadd_rn(cy, r3[u]));
    }

    int o = b * NLOC + q * 4;   // global index = level offset + local loc
    *(float4*)(scores + o) = make_float4(sc4[0], sc4[1], sc4[2], sc4[3]);
    *(int4*)(cls_out + o)  = make_int4(cl4[0], cl4[1], cl4[2], cl4[3]);
#pragma unroll
    for (int u = 0; u < 4; ++u) boxes[o + u] = bx4[u];
}

// ---------------------------------------------------------------------------
// K2 (merged select+prep): per-batch exact top-1000 via radix-select, then
// O(n) rank-by-count (keys unique) instead of bitonic, then gather + maxc +
// class-offset boxes/areas — all in one kernel.
// ---------------------------------------------------------------------------
__global__ __launch_bounds__(1024) void k_select(const uint32_t* scores_u,
                                                 const float4* boxes,
                                                 const int* cls_ws,
                                                 float* topk_score, float4* gbox,
                                                 int* gcls, float4* obox,
                                                 float* areas) {
    __shared__ uint32_t hist[256];
    __shared__ uint32_t cum[256];
    __shared__ uint64_t keys[2048];
    __shared__ uint32_t prefix_sh, cnt_sh;
    __shared__ int R_sh;
    __shared__ float redmax[16];
    __shared__ float maxc_sh;

    int b = blockIdx.x, tid = threadIdx.x;
    const uint4* sc4 = (const uint4*)(scores_u + (size_t)b * NLOC);

    uint32_t prefix = 0;
    int R = MAXDET;
    for (int d = 3; d >= 0; --d) {
        if (tid < 256) hist[tid] = 0;
        __syncthreads();
        int shl = 8 * d;
        int last = -1; uint32_t run = 0;
        for (int n4 = tid; n4 < NQUAD; n4 += 1024) {
            uint4 v = sc4[n4];
            uint32_t vals[4] = {v.x, v.y, v.z, v.w};
#pragma unroll
            for (int u = 0; u < 4; ++u) {
                uint32_t sb = vals[u];
                bool m = (d == 3) || ((sb >> (shl + 8)) == prefix);
                int dig = m ? (int)((sb >> shl) & 255u) : -1;
                if (dig != last) {
                    if (last >= 0 && run) atomicAdd(&hist[last], run);
                    last = dig; run = 0;
                }
                if (dig >= 0) run++;
            }
        }
        if (last >= 0 && run) atomicAdd(&hist[last], run);
        __syncthreads();

        // parallel suffix sum over 256 bins
        if (tid < 256) cum[tid] = hist[tid];
        __syncthreads();
        for (int st = 1; st < 256; st <<= 1) {
            uint32_t v = 0;
            if (tid < 256) v = cum[tid] + ((tid + st < 256) ? cum[tid + st] : 0);
            __syncthreads();
            if (tid < 256) cum[tid] = v;
            __syncthreads();
        }
        if (tid < 256) {
            uint32_t cge  = cum[tid];
            uint32_t cge1 = (tid < 255) ? cum[tid + 1] : 0;
            if (cge >= (uint32_t)R && cge1 < (uint32_t)R) {
                prefix_sh = (prefix << 8) | (uint32_t)tid;
                R_sh = R - (int)cge1;
            }
        }
        __syncthreads();
        prefix = prefix_sh;
        R = R_sh;
        __syncthreads();
    }
    uint32_t Sstar = prefix;

    if (tid == 0) cnt_sh = 0;
    __syncthreads();
    for (int n4 = tid; n4 < NQUAD; n4 += 1024) {
        uint4 v = sc4[n4];
        uint32_t vals[4] = {v.x, v.y, v.z, v.w};
#pragma unroll
        for (int u = 0; u < 4; ++u) {
            uint32_t sb = vals[u];
            if (sb >= Sstar) {
                uint32_t n = (uint32_t)(n4 * 4 + u);
                uint32_t slot = atomicAdd(&cnt_sh, 1u);
                if (slot < 2048)
                    keys[slot] = ((uint64_t)sb << 32) | (uint32_t)(~n);
            }
        }
    }
    __syncthreads();
    uint32_t cnt = cnt_sh > 2048u ? 2048u : cnt_sh;   // cnt >= 1000 by construction

    // rank-by-count: rank = #{keys greater}; keys unique -> ranks unique
    uint64_t myk0 = 0, myk1 = 0;
    bool has0 = tid < (int)cnt, has1 = (tid + 1024) < (int)cnt;
    if (has0) myk0 = keys[tid];
    if (has1) myk1 = keys[tid + 1024];
    int rk0 = 0, rk1 = 0;
    for (uint32_t j = 0; j < cnt; ++j) {      // keys[j] uniform -> LDS broadcast
        uint64_t kj = keys[j];
        rk0 += (kj > myk0);
        rk1 += (kj > myk1);
    }

    float lmax = -3.0e38f;
    float4 v0, v1; int cl0 = 0, cl1 = 0; bool k0 = false, k1 = false;
    if (has0 && rk0 < MAXDET) {
        uint32_t n = ~(uint32_t)myk0;
        v0 = boxes[(size_t)b * NLOC + n];
        cl0 = cls_ws[(size_t)b * NLOC + n];
        topk_score[b * MAXDET + rk0] = __uint_as_float((uint32_t)(myk0 >> 32));
        gbox[b * MAXDET + rk0] = v0;
        gcls[b * MAXDET + rk0] = cl0;
        lmax = fmaxf(fmaxf(v0.x, v0.y), fmaxf(v0.z, v0.w));
        k0 = true;
    }
    if (has1 && rk1 < MAXDET) {
        uint32_t n = ~(uint32_t)myk1;
        v1 = boxes[(size_t)b * NLOC + n];
        cl1 = cls_ws[(size_t)b * NLOC + n];
        topk_score[b * MAXDET + rk1] = __uint_as_float((uint32_t)(myk1 >> 32));
        gbox[b * MAXDET + rk1] = v1;
        gcls[b * MAXDET + rk1] = cl1;
        lmax = fmaxf(lmax, fmaxf(fmaxf(v1.x, v1.y), fmaxf(v1.z, v1.w)));
        k1 = true;
    }

    // block max over all gathered box coords (exact; max has no rounding)
#pragma unroll
    for (int off = 32; off > 0; off >>= 1)
        lmax = fmaxf(lmax, __shfl_down(lmax, off, 64));
    if ((tid & 63) == 0) redmax[tid >> 6] = lmax;
    __syncthreads();
    if (tid == 0) {
        float m = redmax[0];
        for (int w = 1; w < 16; ++w) m = fmaxf(m, redmax[w]);
        maxc_sh = __fadd_rn(m, 1.0f);
    }
    __syncthreads();
    float maxc1 = maxc_sh;

    if (k0) {
        float off0 = __fmul_rn((float)cl0, maxc1);
        float4 o = make_float4(__fadd_rn(v0.x, off0), __fadd_rn(v0.y, off0),
                               __fadd_rn(v0.z, off0), __fadd_rn(v0.w, off0));
        obox[b * MAXDET + rk0] = o;
        areas[b * MAXDET + rk0] =
            __fmul_rn(__fadd_rn(__fsub_rn(o.z, o.x), 1.0f),
                      __fadd_rn(__fsub_rn(o.w, o.y), 1.0f));
    }
    if (k1) {
        float off1 = __fmul_rn((float)cl1, maxc1);
        float4 o = make_float4(__fadd_rn(v1.x, off1), __fadd_rn(v1.y, off1),
                               __fadd_rn(v1.z, off1), __fadd_rn(v1.w, off1));
        obox[b * MAXDET + rk1] = o;
        areas[b * MAXDET + rk1] =
            __fmul_rn(__fadd_rn(__fsub_rn(o.z, o.x), 1.0f),
                      __fadd_rn(__fsub_rn(o.w, o.y), 1.0f));
    }
}

// ---------------------------------------------------------------------------
// K4: suppression bits — one thread computes one (row i, 64-col word) uint64.
// All 1000 boxes staged in LDS (row reads per-lane, column reads broadcast).
// ---------------------------------------------------------------------------
__global__ __launch_bounds__(256) void k_iou(const float4* obox, const float* areas,
                                             uint64_t* rows) {
    __shared__ float4 ob[MAXDET];
    __shared__ float  ca[MAXDET];
    int b = blockIdx.x, word = blockIdx.y, tid = threadIdx.x;
    for (int r = tid; r < MAXDET; r += 256) {
        ob[r] = obox[b * MAXDET + r];
        ca[r] = areas[b * MAXDET + r];
    }
    __syncthreads();

    int j0 = word * 64;
    int jlim = MAXDET - j0;              // valid columns in this word
    if (jlim > 64) jlim = 64;

#pragma unroll
    for (int qr = 0; qr < 4; ++qr) {
        int i = tid + qr * 256;
        if (i >= MAXDET) continue;
        uint64_t rw = 0;
        int jmax = j0 + jlim;            // one past last valid j
        if (i < jmax - 1) {              // any j in word with j > i ?
            float4 bi = ob[i];
            float ai = ca[i];
            for (int jj = 0; jj < jlim; ++jj) {
                int j = j0 + jj;
                float4 bj = ob[j0 + jj];
                float xx1 = fmaxf(bi.x, bj.x), yy1 = fmaxf(bi.y, bj.y);
                float xx2 = fminf(bi.z, bj.z), yy2 = fminf(bi.w, bj.w);
                float w_ = fmaxf(__fsub_rn(xx2, xx1), 0.0f);
                float h_ = fmaxf(__fsub_rn(yy2, yy1), 0.0f);
                float inter = __fmul_rn(w_, h_);
                float denom = __fsub_rn(__fadd_rn(ai, ca[j0 + jj]), inter);
                bool sup = (j > i) && (inter > __fmul_rn(0.6f, denom));
                rw |= sup ? (1ull << jj) : 0ull;
            }
        }
        rows[((size_t)(b * MAXDET) + i) * 16 + word] = rw;
    }
}

// ---------------------------------------------------------------------------
// K5: greedy scan. Lane `word` owns S word in registers -> computes `alive`
// locally (VALU only); broadcast via v_readlane (no ds_bpermute in the chain).
// ---------------------------------------------------------------------------
__global__ __launch_bounds__(256) void k_nms_out(const uint64_t* rows,
                                                 const float* topk_score,
                                                 const int* gcls, const float4* gbox,
                                                 float* out) {
    __shared__ __align__(16) uint64_t rows_lds[8000];   // 500 rows x 16 words
    __shared__ uint64_t validmask[16];
    __shared__ uint64_t keepmask[16];
    int b = blockIdx.x, tid = threadIdx.x;

    if (tid < 16) validmask[tid] = 0;
    __syncthreads();
    for (int r = tid; r < MAXDET; r += 256)
        if (topk_score[b * MAXDET + r] >= 0.05f)
            atomicOr(&validmask[r >> 6], 1ull << (r & 63));
    __syncthreads();

    uint64_t S_reg = 0, K_reg = 0, V_reg = 0;
    if (tid < 16) V_reg = validmask[tid];

    for (int p = 0; p < 2; ++p) {
        const ulonglong2* rg =
            (const ulonglong2*)(rows + ((size_t)(b * MAXDET) + p * 500) * 16);
        for (int w = tid; w < 4000; w += 256)
            ((ulonglong2*)rows_lds)[w] = rg[w];
        __syncthreads();
        if (tid < 64) {
            bool owner = (tid < 16);
            // groups of 8: issue 8 LDS loads, then 8 serial decisions
            for (int ii0 = 0; ii0 < 496; ii0 += 8) {
                uint64_t rwA[4], rwB[4];
#pragma unroll
                for (int u = 0; u < 4; ++u)
                    rwA[u] = owner ? rows_lds[(ii0 + u) * 16 + tid] : 0ull;
#pragma unroll
                for (int u = 0; u < 4; ++u)
                    rwB[u] = owner ? rows_lds[(ii0 + 4 + u) * 16 + tid] : 0ull;
#pragma unroll
                for (int u = 0; u < 8; ++u) {
                    uint64_t rw = (u < 4) ? rwA[u & 3] : rwB[u & 3];
                    int gi = p * 500 + ii0 + u;
                    int word = gi >> 6, bitp = gi & 63;
                    uint32_t aliveV = ((uint32_t)(V_reg >> bitp) &
                                       ~(uint32_t)(S_reg >> bitp)) & 1u;
                    uint32_t alive =
                        (uint32_t)__builtin_amdgcn_readlane((int)aliveV, word);
                    if (alive) {                         // uniform (SGPR) branch
                        S_reg |= rw;
                        if (tid == word) K_reg |= (1ull << bitp);
                    }
                }
            }
            // tail rows 496..499 of this pass
            {
                uint64_t rwA[4];
#pragma unroll
                for (int u = 0; u < 4; ++u)
                    rwA[u] = owner ? rows_lds[(496 + u) * 16 + tid] : 0ull;
#pragma unroll
                for (int u = 0; u < 4; ++u) {
                    int gi = p * 500 + 496 + u;
                    int word = gi >> 6, bitp = gi & 63;
                    uint32_t aliveV = ((uint32_t)(V_reg >> bitp) &
                                       ~(uint32_t)(S_reg >> bitp)) & 1u;
                    uint32_t alive =
                        (uint32_t)__builtin_amdgcn_readlane((int)aliveV, word);
                    if (alive) {
                        S_reg |= rwA[u];
                        if (tid == word) K_reg |= (1ull << bitp);
                    }
                }
            }
        }
        __syncthreads();
    }
    if (tid < 16) keepmask[tid] = K_reg;
    __syncthreads();

    for (int r = tid; r < MAXDET; r += 256) {
        bool keep = ((keepmask[r >> 6] >> (r & 63)) & 1ull) != 0;
        float sc = topk_score[b * MAXDET + r];
        int cl = gcls[b * MAXDET + r];
        float4 v = gbox[b * MAXDET + r];
        float c0 = fminf(fmaxf(v.x, 0.0f), 1023.0f);
        float c1 = fminf(fmaxf(v.y, 0.0f), 1023.0f);
        float c2 = fminf(fmaxf(v.z, 0.0f), 1023.0f);
        float c3 = fminf(fmaxf(v.w, 0.0f), 1023.0f);
        out[b * MAXDET + r] = keep ? sc : 0.0f;
        out[BATCH * MAXDET + b * MAXDET + r] = keep ? (float)cl : 0.0f;
        float4* op = (float4*)(out + 2 * BATCH * MAXDET) + (b * MAXDET + r);
        *op = keep ? make_float4(c0, c1, c2, c3) : make_float4(0.f, 0.f, 0.f, 0.f);
    }
}

// ---------------------------------------------------------------------------
extern "C" void kernel_launch(void* const* d_in, const int* in_sizes, int n_in,
                              void* d_out, int out_size, void* d_ws, size_t ws_size,
                              hipStream_t stream) {
    (void)in_sizes; (void)n_in; (void)out_size; (void)ws_size;

    LevelPtrs lp;
    for (int i = 0; i < 5; ++i) {
        lp.cls[i] = (const float*)d_in[3 * i + 0];
        lp.cnt[i] = (const float*)d_in[3 * i + 1];
        lp.reg[i] = (const float*)d_in[3 * i + 2];
    }

    char* ws = (char*)d_ws;
    float*    scores   = (float*)   (ws + 0);          // 8*21824*4   = 698368
    int*      cls_ws   = (int*)     (ws + 698368);     // 698368
    float4*   boxes    = (float4*)  (ws + 1396736);    // 8*21824*16  = 2793472
    float*    topk_sc  = (float*)   (ws + 4222208);    // 32000
    int*      gcls     = (int*)     (ws + 4254208);    // 32000
    float4*   gbox     = (float4*)  (ws + 4286208);    // 128000
    float4*   obox     = (float4*)  (ws + 4414208);    // 128000
    float*    areas    = (float*)   (ws + 4542208);    // 32000
    uint64_t* rows     = (uint64_t*)(ws + 4574208);    // 8*1000*16*8 = 1024000

    dim3 g1((NQUAD + 127) / 128, BATCH);
    k_stage1<<<g1, 128, 0, stream>>>(lp, scores, cls_ws, boxes);

    k_select<<<BATCH, 1024, 0, stream>>>((const uint32_t*)scores, boxes, cls_ws,
                                         topk_sc, gbox, gcls, obox, areas);

    dim3 g4(BATCH, 16);
    k_iou<<<g4, 256, 0, stream>>>(obox, areas, rows);

    k_nms_out<<<BATCH, 256, 0, stream>>>(rows, topk_sc, gcls, gbox, (float*)d_out);
}

// Round 6
// 336.618 us; speedup vs baseline: 2.1048x; 1.1574x over previous
//
#include <hip/hip_runtime.h>
#include <stdint.h>

#define NLOC   21824
#define NQUAD  5456          // NLOC/4
#define BATCH  8
#define MAXDET 1000
#define NCLS   80

struct LevelPtrs {
    const float* cls[5];
    const float* cnt[5];
    const float* reg[5];
};

// ---------------------------------------------------------------------------
// K1: per-location score/class/box. Block = 8 class-partitions x 32 quads.
// Argmax over RAW LOGITS (sigmoid strictly monotone -> same argmax/max);
// sigmoid computed once per location in the epilogue with the identical
// expf/div/__fmul_rn/sqrtf sequence as before (bit-identical scores).
// ---------------------------------------------------------------------------
__global__ __launch_bounds__(256) void k_stage1(LevelPtrs lp, float* scores,
                                                int* cls_out, float4* boxes) {
    __shared__ float4 bl4[8][32];   // best logit per (partition, quad) x4 locs
    __shared__ int4   bc4[8][32];   // best class
    int tid = threadIdx.x;
    int p   = tid >> 5;             // class partition 0..7 (classes p*10..p*10+9)
    int qq  = tid & 31;             // quad within block
    int blk = blockIdx.x;
    int b   = blockIdx.y;

    int lvl, qoff, logw, strd;
    if (blk < 128)      { lvl = 0; qoff = 0;    logw = 7; strd = 8;   }
    else if (blk < 160) { lvl = 1; qoff = 4096; logw = 6; strd = 16;  }
    else if (blk < 168) { lvl = 2; qoff = 5120; logw = 5; strd = 32;  }
    else if (blk < 170) { lvl = 3; qoff = 5376; logw = 4; strd = 64;  }
    else                { lvl = 4; qoff = 5440; logw = 3; strd = 128; }

    int quad  = blk * 32 + qq;            // global quad id
    bool valid = quad < NQUAD;            // only last block partial
    int ql   = quad - qoff;               // level-local quad
    int loc  = ql * 4;                    // level-local location (4 consecutive)
    int hw   = 1 << (2 * logw);
    int hw4  = hw >> 2;

    float bl[4] = {-3.0e38f, -3.0e38f, -3.0e38f, -3.0e38f};
    int   bc[4] = {0, 0, 0, 0};
    if (valid) {
        const float4* cp = (const float4*)(lp.cls[lvl] + (size_t)(b * NCLS) * hw + loc);
        int c0 = p * 10;
#pragma unroll
        for (int g = 0; g < 2; ++g) {
            float4 lv[5];
#pragma unroll
            for (int k = 0; k < 5; ++k)
                lv[k] = cp[(size_t)(c0 + g * 5 + k) * hw4];
#pragma unroll
            for (int k = 0; k < 5; ++k) {
                int c = c0 + g * 5 + k;
                const float* lf = (const float*)&lv[k];
#pragma unroll
                for (int u = 0; u < 4; ++u)
                    if (lf[u] > bl[u]) { bl[u] = lf[u]; bc[u] = c; }   // strict > : first index
            }
        }
    }
    bl4[p][qq] = make_float4(bl[0], bl[1], bl[2], bl[3]);
    bc4[p][qq] = make_int4(bc[0], bc[1], bc[2], bc[3]);
    __syncthreads();

    // epilogue: threads 0..31 merge 8 partitions (ascending class ranges,
    // strict > keeps lowest class on ties) + compute score/box, store
    if (tid < 32 && valid) {
        int q = tid;
        float4 B = bl4[0][q]; int4 C = bc4[0][q];
        float bestl[4] = {B.x, B.y, B.z, B.w};
        int   bestc[4] = {C.x, C.y, C.z, C.w};
#pragma unroll
        for (int pp = 1; pp < 8; ++pp) {
            float4 Bp = bl4[pp][q]; int4 Cp = bc4[pp][q];
            const float* bf = (const float*)&Bp;
            const int*   cf = (const int*)&Cp;
#pragma unroll
            for (int u = 0; u < 4; ++u)
                if (bf[u] > bestl[u]) { bestl[u] = bf[u]; bestc[u] = cf[u]; }
        }

        float4 lcv = *(const float4*)(lp.cnt[lvl] + (size_t)b * hw + loc);
        const float* lc = (const float*)&lcv;

        const float4* rp = (const float4*)(lp.reg[lvl] + (size_t)(b * 4) * hw + loc);
        float4 r0v = rp[0], r1v = rp[hw4], r2v = rp[2 * hw4], r3v = rp[3 * hw4];
        const float* r0 = (const float*)&r0v;
        const float* r1 = (const float*)&r1v;
        const float* r2 = (const float*)&r2v;
        const float* r3 = (const float*)&r3v;

        int x = loc & ((1 << logw) - 1);
        int y = loc >> logw;
        float cy = (float)(y * strd + (strd >> 1));

        float sc4[4]; int cl4[4]; float4 bx4[4];
#pragma unroll
        for (int u = 0; u < 4; ++u) {
            float e = expf(-bestl[u]);
            float sig_cls = 1.0f / (1.0f + e);
            float sig_cnt = 1.0f / (1.0f + expf(-lc[u]));
            sc4[u] = sqrtf(__fmul_rn(sig_cls, sig_cnt));
            cl4[u] = bestc[u] + 1;
            float cx = (float)((x + u) * strd + (strd >> 1));
            bx4[u] = make_float4(__fsub_rn(cx, r0[u]), __fsub_rn(cy, r1[u]),
                                 __fadd_rn(cx, r2[u]), __fadd_rn(cy, r3[u]));
        }

        int o = b * NLOC + quad * 4;     // global index = level offset + local loc
        *(float4*)(scores + o) = make_float4(sc4[0], sc4[1], sc4[2], sc4[3]);
        *(int4*)(cls_out + o)  = make_int4(cl4[0], cl4[1], cl4[2], cl4[3]);
#pragma unroll
        for (int u = 0; u < 4; ++u) boxes[o + u] = bx4[u];
    }
}

// ---------------------------------------------------------------------------
// K2 (merged select+prep): per-batch exact top-1000 via radix-select, then
// O(n) rank-by-count (keys unique) instead of bitonic, then gather + maxc +
// class-offset boxes/areas — all in one kernel.
// ---------------------------------------------------------------------------
__global__ __launch_bounds__(1024) void k_select(const uint32_t* scores_u,
                                                 const float4* boxes,
                                                 const int* cls_ws,
                                                 float* topk_score, float4* gbox,
                                                 int* gcls, float4* obox,
                                                 float* areas) {
    __shared__ uint32_t hist[256];
    __shared__ uint32_t cum[256];
    __shared__ uint64_t keys[2048];
    __shared__ uint32_t prefix_sh, cnt_sh;
    __shared__ int R_sh;
    __shared__ float redmax[16];
    __shared__ float maxc_sh;

    int b = blockIdx.x, tid = threadIdx.x;
    const uint4* sc4 = (const uint4*)(scores_u + (size_t)b * NLOC);

    uint32_t prefix = 0;
    int R = MAXDET;
    for (int d = 3; d >= 0; --d) {
        if (tid < 256) hist[tid] = 0;
        __syncthreads();
        int shl = 8 * d;
        int last = -1; uint32_t run = 0;
        for (int n4 = tid; n4 < NQUAD; n4 += 1024) {
            uint4 v = sc4[n4];
            uint32_t vals[4] = {v.x, v.y, v.z, v.w};
#pragma unroll
            for (int u = 0; u < 4; ++u) {
                uint32_t sb = vals[u];
                bool m = (d == 3) || ((sb >> (shl + 8)) == prefix);
                int dig = m ? (int)((sb >> shl) & 255u) : -1;
                if (dig != last) {
                    if (last >= 0 && run) atomicAdd(&hist[last], run);
                    last = dig; run = 0;
                }
                if (dig >= 0) run++;
            }
        }
        if (last >= 0 && run) atomicAdd(&hist[last], run);
        __syncthreads();

        if (tid < 256) cum[tid] = hist[tid];
        __syncthreads();
        for (int st = 1; st < 256; st <<= 1) {
            uint32_t v = 0;
            if (tid < 256) v = cum[tid] + ((tid + st < 256) ? cum[tid + st] : 0);
            __syncthreads();
            if (tid < 256) cum[tid] = v;
            __syncthreads();
        }
        if (tid < 256) {
            uint32_t cge  = cum[tid];
            uint32_t cge1 = (tid < 255) ? cum[tid + 1] : 0;
            if (cge >= (uint32_t)R && cge1 < (uint32_t)R) {
                prefix_sh = (prefix << 8) | (uint32_t)tid;
                R_sh = R - (int)cge1;
            }
        }
        __syncthreads();
        prefix = prefix_sh;
        R = R_sh;
        __syncthreads();
    }
    uint32_t Sstar = prefix;

    if (tid == 0) cnt_sh = 0;
    __syncthreads();
    for (int n4 = tid; n4 < NQUAD; n4 += 1024) {
        uint4 v = sc4[n4];
        uint32_t vals[4] = {v.x, v.y, v.z, v.w};
#pragma unroll
        for (int u = 0; u < 4; ++u) {
            uint32_t sb = vals[u];
            if (sb >= Sstar) {
                uint32_t n = (uint32_t)(n4 * 4 + u);
                uint32_t slot = atomicAdd(&cnt_sh, 1u);
                if (slot < 2048)
                    keys[slot] = ((uint64_t)sb << 32) | (uint32_t)(~n);
            }
        }
    }
    __syncthreads();
    uint32_t cnt = cnt_sh > 2048u ? 2048u : cnt_sh;   // cnt >= 1000 by construction

    // rank-by-count: rank = #{keys greater}; keys unique -> ranks unique
    uint64_t myk0 = 0, myk1 = 0;
    bool has0 = tid < (int)cnt, has1 = (tid + 1024) < (int)cnt;
    if (has0) myk0 = keys[tid];
    if (has1) myk1 = keys[tid + 1024];
    int rk0 = 0, rk1 = 0;
    for (uint32_t j = 0; j < cnt; ++j) {      // keys[j] uniform -> LDS broadcast
        uint64_t kj = keys[j];
        rk0 += (kj > myk0);
        rk1 += (kj > myk1);
    }

    float lmax = -3.0e38f;
    float4 v0, v1; int cl0 = 0, cl1 = 0; bool k0 = false, k1 = false;
    int rkk0 = 0, rkk1 = 0;
    if (has0 && rk0 < MAXDET) {
        uint32_t n = ~(uint32_t)myk0;
        v0 = boxes[(size_t)b * NLOC + n];
        cl0 = cls_ws[(size_t)b * NLOC + n];
        topk_score[b * MAXDET + rk0] = __uint_as_float((uint32_t)(myk0 >> 32));
        gbox[b * MAXDET + rk0] = v0;
        gcls[b * MAXDET + rk0] = cl0;
        lmax = fmaxf(fmaxf(v0.x, v0.y), fmaxf(v0.z, v0.w));
        k0 = true; rkk0 = rk0;
    }
    if (has1 && rk1 < MAXDET) {
        uint32_t n = ~(uint32_t)myk1;
        v1 = boxes[(size_t)b * NLOC + n];
        cl1 = cls_ws[(size_t)b * NLOC + n];
        topk_score[b * MAXDET + rk1] = __uint_as_float((uint32_t)(myk1 >> 32));
        gbox[b * MAXDET + rk1] = v1;
        gcls[b * MAXDET + rk1] = cl1;
        lmax = fmaxf(lmax, fmaxf(fmaxf(v1.x, v1.y), fmaxf(v1.z, v1.w)));
        k1 = true; rkk1 = rk1;
    }

#pragma unroll
    for (int off = 32; off > 0; off >>= 1)
        lmax = fmaxf(lmax, __shfl_down(lmax, off, 64));
    if ((tid & 63) == 0) redmax[tid >> 6] = lmax;
    __syncthreads();
    if (tid == 0) {
        float m = redmax[0];
        for (int w = 1; w < 16; ++w) m = fmaxf(m, redmax[w]);
        maxc_sh = __fadd_rn(m, 1.0f);
    }
    __syncthreads();
    float maxc1 = maxc_sh;

    if (k0) {
        float off0 = __fmul_rn((float)cl0, maxc1);
        float4 o = make_float4(__fadd_rn(v0.x, off0), __fadd_rn(v0.y, off0),
                               __fadd_rn(v0.z, off0), __fadd_rn(v0.w, off0));
        obox[b * MAXDET + rkk0] = o;
        areas[b * MAXDET + rkk0] =
            __fmul_rn(__fadd_rn(__fsub_rn(o.z, o.x), 1.0f),
                      __fadd_rn(__fsub_rn(o.w, o.y), 1.0f));
    }
    if (k1) {
        float off1 = __fmul_rn((float)cl1, maxc1);
        float4 o = make_float4(__fadd_rn(v1.x, off1), __fadd_rn(v1.y, off1),
                               __fadd_rn(v1.z, off1), __fadd_rn(v1.w, off1));
        obox[b * MAXDET + rkk1] = o;
        areas[b * MAXDET + rkk1] =
            __fmul_rn(__fadd_rn(__fsub_rn(o.z, o.x), 1.0f),
                      __fadd_rn(__fsub_rn(o.w, o.y), 1.0f));
    }
}

// ---------------------------------------------------------------------------
// K4: suppression bits — one thread computes one (row i, 64-col word) uint64.
// All 1000 boxes staged in LDS (row reads per-lane, column reads broadcast).
// ---------------------------------------------------------------------------
__global__ __launch_bounds__(256) void k_iou(const float4* obox, const float* areas,
                                             uint64_t* rows) {
    __shared__ float4 ob[MAXDET];
    __shared__ float  ca[MAXDET];
    int b = blockIdx.x, word = blockIdx.y, tid = threadIdx.x;
    for (int r = tid; r < MAXDET; r += 256) {
        ob[r] = obox[b * MAXDET + r];
        ca[r] = areas[b * MAXDET + r];
    }
    __syncthreads();

    int j0 = word * 64;
    int jlim = MAXDET - j0;
    if (jlim > 64) jlim = 64;

#pragma unroll
    for (int qr = 0; qr < 4; ++qr) {
        int i = tid + qr * 256;
        if (i >= MAXDET) continue;
        uint64_t rw = 0;
        int jmax = j0 + jlim;
        if (i < jmax - 1) {
            float4 bi = ob[i];
            float ai = ca[i];
            for (int jj = 0; jj < jlim; ++jj) {
                int j = j0 + jj;
                float4 bj = ob[j0 + jj];
                float xx1 = fmaxf(bi.x, bj.x), yy1 = fmaxf(bi.y, bj.y);
                float xx2 = fminf(bi.z, bj.z), yy2 = fminf(bi.w, bj.w);
                float w_ = fmaxf(__fsub_rn(xx2, xx1), 0.0f);
                float h_ = fmaxf(__fsub_rn(yy2, yy1), 0.0f);
                float inter = __fmul_rn(w_, h_);
                float denom = __fsub_rn(__fadd_rn(ai, ca[j0 + jj]), inter);
                bool sup = (j > i) && (inter > __fmul_rn(0.6f, denom));
                rw |= sup ? (1ull << jj) : 0ull;
            }
        }
        rows[((size_t)(b * MAXDET) + i) * 16 + word] = rw;
    }
}

// ---------------------------------------------------------------------------
// K5: greedy scan. Lane `word` owns S word in registers -> computes `alive`
// locally (VALU only); broadcast via v_readlane (no ds_bpermute in the chain).
// ---------------------------------------------------------------------------
__global__ __launch_bounds__(256) void k_nms_out(const uint64_t* rows,
                                                 const float* topk_score,
                                                 const int* gcls, const float4* gbox,
                                                 float* out) {
    __shared__ __align__(16) uint64_t rows_lds[8000];
    __shared__ uint64_t validmask[16];
    __shared__ uint64_t keepmask[16];
    int b = blockIdx.x, tid = threadIdx.x;

    if (tid < 16) validmask[tid] = 0;
    __syncthreads();
    for (int r = tid; r < MAXDET; r += 256)
        if (topk_score[b * MAXDET + r] >= 0.05f)
            atomicOr(&validmask[r >> 6], 1ull << (r & 63));
    __syncthreads();

    uint64_t S_reg = 0, K_reg = 0, V_reg = 0;
    if (tid < 16) V_reg = validmask[tid];

    for (int p = 0; p < 2; ++p) {
        const ulonglong2* rg =
            (const ulonglong2*)(rows + ((size_t)(b * MAXDET) + p * 500) * 16);
        for (int w = tid; w < 4000; w += 256)
            ((ulonglong2*)rows_lds)[w] = rg[w];
        __syncthreads();
        if (tid < 64) {
            bool owner = (tid < 16);
            for (int ii0 = 0; ii0 < 496; ii0 += 8) {
                uint64_t rwA[4], rwB[4];
#pragma unroll
                for (int u = 0; u < 4; ++u)
                    rwA[u] = owner ? rows_lds[(ii0 + u) * 16 + tid] : 0ull;
#pragma unroll
                for (int u = 0; u < 4; ++u)
                    rwB[u] = owner ? rows_lds[(ii0 + 4 + u) * 16 + tid] : 0ull;
#pragma unroll
                for (int u = 0; u < 8; ++u) {
                    uint64_t rw = (u < 4) ? rwA[u & 3] : rwB[u & 3];
                    int gi = p * 500 + ii0 + u;
                    int word = gi >> 6, bitp = gi & 63;
                    uint32_t aliveV = ((uint32_t)(V_reg >> bitp) &
                                       ~(uint32_t)(S_reg >> bitp)) & 1u;
                    uint32_t alive =
                        (uint32_t)__builtin_amdgcn_readlane((int)aliveV, word);
                    if (alive) {
                        S_reg |= rw;
                        if (tid == word) K_reg |= (1ull << bitp);
                    }
                }
            }
            {
                uint64_t rwA[4];
#pragma unroll
                for (int u = 0; u < 4; ++u)
                    rwA[u] = owner ? rows_lds[(496 + u) * 16 + tid] : 0ull;
#pragma unroll
                for (int u = 0; u < 4; ++u) {
                    int gi = p * 500 + 496 + u;
                    int word = gi >> 6, bitp = gi & 63;
                    uint32_t aliveV = ((uint32_t)(V_reg >> bitp) &
                                       ~(uint32_t)(S_reg >> bitp)) & 1u;
                    uint32_t alive =
                        (uint32_t)__builtin_amdgcn_readlane((int)aliveV, word);
                    if (alive) {
                        S_reg |= rwA[u];
                        if (tid == word) K_reg |= (1ull << bitp);
                    }
                }
            }
        }
        __syncthreads();
    }
    if (tid < 16) keepmask[tid] = K_reg;
    __syncthreads();

    for (int r = tid; r < MAXDET; r += 256) {
        bool keep = ((keepmask[r >> 6] >> (r & 63)) & 1ull) != 0;
        float sc = topk_score[b * MAXDET + r];
        int cl = gcls[b * MAXDET + r];
        float4 v = gbox[b * MAXDET + r];
        float c0 = fminf(fmaxf(v.x, 0.0f), 1023.0f);
        float c1 = fminf(fmaxf(v.y, 0.0f), 1023.0f);
        float c2 = fminf(fmaxf(v.z, 0.0f), 1023.0f);
        float c3 = fminf(fmaxf(v.w, 0.0f), 1023.0f);
        out[b * MAXDET + r] = keep ? sc : 0.0f;
        out[BATCH * MAXDET + b * MAXDET + r] = keep ? (float)cl : 0.0f;
        float4* op = (float4*)(out + 2 * BATCH * MAXDET) + (b * MAXDET + r);
        *op = keep ? make_float4(c0, c1, c2, c3) : make_float4(0.f, 0.f, 0.f, 0.f);
    }
}

// ---------------------------------------------------------------------------
extern "C" void kernel_launch(void* const* d_in, const int* in_sizes, int n_in,
                              void* d_out, int out_size, void* d_ws, size_t ws_size,
                              hipStream_t stream) {
    (void)in_sizes; (void)n_in; (void)out_size; (void)ws_size;

    LevelPtrs lp;
    for (int i = 0; i < 5; ++i) {
        lp.cls[i] = (const float*)d_in[3 * i + 0];
        lp.cnt[i] = (const float*)d_in[3 * i + 1];
        lp.reg[i] = (const float*)d_in[3 * i + 2];
    }

    char* ws = (char*)d_ws;
    float*    scores   = (float*)   (ws + 0);          // 8*21824*4   = 698368
    int*      cls_ws   = (int*)     (ws + 698368);     // 698368
    float4*   boxes    = (float4*)  (ws + 1396736);    // 8*21824*16  = 2793472
    float*    topk_sc  = (float*)   (ws + 4222208);    // 32000
    int*      gcls     = (int*)     (ws + 4254208);    // 32000
    float4*   gbox     = (float4*)  (ws + 4286208);    // 128000
    float4*   obox     = (float4*)  (ws + 4414208);    // 128000
    float*    areas    = (float*)   (ws + 4542208);    // 32000
    uint64_t* rows     = (uint64_t*)(ws + 4574208);    // 8*1000*16*8 = 1024000

    dim3 g1(171, BATCH);   // 171 blocks x 32 quads = 5472 >= NQUAD
    k_stage1<<<g1, 256, 0, stream>>>(lp, scores, cls_ws, boxes);

    k_select<<<BATCH, 1024, 0, stream>>>((const uint32_t*)scores, boxes, cls_ws,
                                         topk_sc, gbox, gcls, obox, areas);

    dim3 g4(BATCH, 16);
    k_iou<<<g4, 256, 0, stream>>>(obox, areas, rows);

    k_nms_out<<<BATCH, 256, 0, stream>>>(rows, topk_sc, gcls, gbox, (float*)d_out);
}

// Round 7
// 272.183 us; speedup vs baseline: 2.6031x; 1.2367x over previous
//
#include <hip/hip_runtime.h>
#include <stdint.h>

#define NLOC   21824
#define NQUAD  5456          // NLOC/4
#define BATCH  8
#define MAXDET 1000
#define NCLS   80

struct LevelPtrs {
    const float* cls[5];
    const float* cnt[5];
    const float* reg[5];
};

// ---------------------------------------------------------------------------
// K1: per-location score/class/box. Block = 8 class-partitions x 32 quads.
// Argmax over RAW LOGITS (sigmoid strictly monotone); sigmoid once per
// location in the epilogue (bit-identical scores).
// ---------------------------------------------------------------------------
__global__ __launch_bounds__(256) void k_stage1(LevelPtrs lp, float* scores,
                                                int* cls_out, float4* boxes) {
    __shared__ float4 bl4[8][32];
    __shared__ int4   bc4[8][32];
    int tid = threadIdx.x;
    int p   = tid >> 5;             // class partition (classes p*10..p*10+9)
    int qq  = tid & 31;
    int blk = blockIdx.x;
    int b   = blockIdx.y;

    int lvl, qoff, logw, strd;
    if (blk < 128)      { lvl = 0; qoff = 0;    logw = 7; strd = 8;   }
    else if (blk < 160) { lvl = 1; qoff = 4096; logw = 6; strd = 16;  }
    else if (blk < 168) { lvl = 2; qoff = 5120; logw = 5; strd = 32;  }
    else if (blk < 170) { lvl = 3; qoff = 5376; logw = 4; strd = 64;  }
    else                { lvl = 4; qoff = 5440; logw = 3; strd = 128; }

    int quad  = blk * 32 + qq;
    bool valid = quad < NQUAD;
    int ql   = quad - qoff;
    int loc  = ql * 4;
    int hw   = 1 << (2 * logw);
    int hw4  = hw >> 2;

    float bl[4] = {-3.0e38f, -3.0e38f, -3.0e38f, -3.0e38f};
    int   bc[4] = {0, 0, 0, 0};
    if (valid) {
        const float4* cp = (const float4*)(lp.cls[lvl] + (size_t)(b * NCLS) * hw + loc);
        int c0 = p * 10;
#pragma unroll
        for (int g = 0; g < 2; ++g) {
            float4 lv[5];
#pragma unroll
            for (int k = 0; k < 5; ++k)
                lv[k] = cp[(size_t)(c0 + g * 5 + k) * hw4];
#pragma unroll
            for (int k = 0; k < 5; ++k) {
                int c = c0 + g * 5 + k;
                const float* lf = (const float*)&lv[k];
#pragma unroll
                for (int u = 0; u < 4; ++u)
                    if (lf[u] > bl[u]) { bl[u] = lf[u]; bc[u] = c; }
            }
        }
    }
    bl4[p][qq] = make_float4(bl[0], bl[1], bl[2], bl[3]);
    bc4[p][qq] = make_int4(bc[0], bc[1], bc[2], bc[3]);
    __syncthreads();

    if (tid < 32 && valid) {
        int q = tid;
        float4 B = bl4[0][q]; int4 C = bc4[0][q];
        float bestl[4] = {B.x, B.y, B.z, B.w};
        int   bestc[4] = {C.x, C.y, C.z, C.w};
#pragma unroll
        for (int pp = 1; pp < 8; ++pp) {
            float4 Bp = bl4[pp][q]; int4 Cp = bc4[pp][q];
            const float* bf = (const float*)&Bp;
            const int*   cf = (const int*)&Cp;
#pragma unroll
            for (int u = 0; u < 4; ++u)
                if (bf[u] > bestl[u]) { bestl[u] = bf[u]; bestc[u] = cf[u]; }
        }

        float4 lcv = *(const float4*)(lp.cnt[lvl] + (size_t)b * hw + loc);
        const float* lc = (const float*)&lcv;

        const float4* rp = (const float4*)(lp.reg[lvl] + (size_t)(b * 4) * hw + loc);
        float4 r0v = rp[0], r1v = rp[hw4], r2v = rp[2 * hw4], r3v = rp[3 * hw4];
        const float* r0 = (const float*)&r0v;
        const float* r1 = (const float*)&r1v;
        const float* r2 = (const float*)&r2v;
        const float* r3 = (const float*)&r3v;

        int x = loc & ((1 << logw) - 1);
        int y = loc >> logw;
        float cy = (float)(y * strd + (strd >> 1));

        float sc4[4]; int cl4[4]; float4 bx4[4];
#pragma unroll
        for (int u = 0; u < 4; ++u) {
            float e = expf(-bestl[u]);
            float sig_cls = 1.0f / (1.0f + e);
            float sig_cnt = 1.0f / (1.0f + expf(-lc[u]));
            sc4[u] = sqrtf(__fmul_rn(sig_cls, sig_cnt));
            cl4[u] = bestc[u] + 1;
            float cx = (float)((x + u) * strd + (strd >> 1));
            bx4[u] = make_float4(__fsub_rn(cx, r0[u]), __fsub_rn(cy, r1[u]),
                                 __fadd_rn(cx, r2[u]), __fadd_rn(cy, r3[u]));
        }

        int o = b * NLOC + quad * 4;
        *(float4*)(scores + o) = make_float4(sc4[0], sc4[1], sc4[2], sc4[3]);
        *(int4*)(cls_out + o)  = make_int4(cl4[0], cl4[1], cl4[2], cl4[3]);
#pragma unroll
        for (int u = 0; u < 4; ++u) boxes[o + u] = bx4[u];
    }
}

// ---------------------------------------------------------------------------
// K2 (merged select+prep): exact top-1000 radix-select + rank-by-count +
// gather + maxc + class-offset boxes/areas. Also zeroes nzmask for k_iou.
// ---------------------------------------------------------------------------
__global__ __launch_bounds__(1024) void k_select(const uint32_t* scores_u,
                                                 const float4* boxes,
                                                 const int* cls_ws,
                                                 float* topk_score, float4* gbox,
                                                 int* gcls, float4* obox,
                                                 float* areas, uint64_t* nzmask) {
    __shared__ uint32_t hist[256];
    __shared__ uint32_t cum[256];
    __shared__ uint64_t keys[2048];
    __shared__ uint32_t prefix_sh, cnt_sh;
    __shared__ int R_sh;
    __shared__ float redmax[16];
    __shared__ float maxc_sh;

    int b = blockIdx.x, tid = threadIdx.x;
    if (tid < 16) nzmask[b * 16 + tid] = 0;   // consumed by k_iou (later dispatch)
    const uint4* sc4 = (const uint4*)(scores_u + (size_t)b * NLOC);

    uint32_t prefix = 0;
    int R = MAXDET;
    for (int d = 3; d >= 0; --d) {
        if (tid < 256) hist[tid] = 0;
        __syncthreads();
        int shl = 8 * d;
        int last = -1; uint32_t run = 0;
        for (int n4 = tid; n4 < NQUAD; n4 += 1024) {
            uint4 v = sc4[n4];
            uint32_t vals[4] = {v.x, v.y, v.z, v.w};
#pragma unroll
            for (int u = 0; u < 4; ++u) {
                uint32_t sb = vals[u];
                bool m = (d == 3) || ((sb >> (shl + 8)) == prefix);
                int dig = m ? (int)((sb >> shl) & 255u) : -1;
                if (dig != last) {
                    if (last >= 0 && run) atomicAdd(&hist[last], run);
                    last = dig; run = 0;
                }
                if (dig >= 0) run++;
            }
        }
        if (last >= 0 && run) atomicAdd(&hist[last], run);
        __syncthreads();

        if (tid < 256) cum[tid] = hist[tid];
        __syncthreads();
        for (int st = 1; st < 256; st <<= 1) {
            uint32_t v = 0;
            if (tid < 256) v = cum[tid] + ((tid + st < 256) ? cum[tid + st] : 0);
            __syncthreads();
            if (tid < 256) cum[tid] = v;
            __syncthreads();
        }
        if (tid < 256) {
            uint32_t cge  = cum[tid];
            uint32_t cge1 = (tid < 255) ? cum[tid + 1] : 0;
            if (cge >= (uint32_t)R && cge1 < (uint32_t)R) {
                prefix_sh = (prefix << 8) | (uint32_t)tid;
                R_sh = R - (int)cge1;
            }
        }
        __syncthreads();
        prefix = prefix_sh;
        R = R_sh;
        __syncthreads();
    }
    uint32_t Sstar = prefix;

    if (tid == 0) cnt_sh = 0;
    __syncthreads();
    for (int n4 = tid; n4 < NQUAD; n4 += 1024) {
        uint4 v = sc4[n4];
        uint32_t vals[4] = {v.x, v.y, v.z, v.w};
#pragma unroll
        for (int u = 0; u < 4; ++u) {
            uint32_t sb = vals[u];
            if (sb >= Sstar) {
                uint32_t n = (uint32_t)(n4 * 4 + u);
                uint32_t slot = atomicAdd(&cnt_sh, 1u);
                if (slot < 2048)
                    keys[slot] = ((uint64_t)sb << 32) | (uint32_t)(~n);
            }
        }
    }
    __syncthreads();
    uint32_t cnt = cnt_sh > 2048u ? 2048u : cnt_sh;

    uint64_t myk0 = 0, myk1 = 0;
    bool has0 = tid < (int)cnt, has1 = (tid + 1024) < (int)cnt;
    if (has0) myk0 = keys[tid];
    if (has1) myk1 = keys[tid + 1024];
    int rk0 = 0, rk1 = 0;
    for (uint32_t j = 0; j < cnt; ++j) {
        uint64_t kj = keys[j];
        rk0 += (kj > myk0);
        rk1 += (kj > myk1);
    }

    float lmax = -3.0e38f;
    float4 v0, v1; int cl0 = 0, cl1 = 0; bool k0 = false, k1 = false;
    if (has0 && rk0 < MAXDET) {
        uint32_t n = ~(uint32_t)myk0;
        v0 = boxes[(size_t)b * NLOC + n];
        cl0 = cls_ws[(size_t)b * NLOC + n];
        topk_score[b * MAXDET + rk0] = __uint_as_float((uint32_t)(myk0 >> 32));
        gbox[b * MAXDET + rk0] = v0;
        gcls[b * MAXDET + rk0] = cl0;
        lmax = fmaxf(fmaxf(v0.x, v0.y), fmaxf(v0.z, v0.w));
        k0 = true;
    }
    if (has1 && rk1 < MAXDET) {
        uint32_t n = ~(uint32_t)myk1;
        v1 = boxes[(size_t)b * NLOC + n];
        cl1 = cls_ws[(size_t)b * NLOC + n];
        topk_score[b * MAXDET + rk1] = __uint_as_float((uint32_t)(myk1 >> 32));
        gbox[b * MAXDET + rk1] = v1;
        gcls[b * MAXDET + rk1] = cl1;
        lmax = fmaxf(lmax, fmaxf(fmaxf(v1.x, v1.y), fmaxf(v1.z, v1.w)));
        k1 = true;
    }

#pragma unroll
    for (int off = 32; off > 0; off >>= 1)
        lmax = fmaxf(lmax, __shfl_down(lmax, off, 64));
    if ((tid & 63) == 0) redmax[tid >> 6] = lmax;
    __syncthreads();
    if (tid == 0) {
        float m = redmax[0];
        for (int w = 1; w < 16; ++w) m = fmaxf(m, redmax[w]);
        maxc_sh = __fadd_rn(m, 1.0f);
    }
    __syncthreads();
    float maxc1 = maxc_sh;

    if (k0) {
        float off0 = __fmul_rn((float)cl0, maxc1);
        float4 o = make_float4(__fadd_rn(v0.x, off0), __fadd_rn(v0.y, off0),
                               __fadd_rn(v0.z, off0), __fadd_rn(v0.w, off0));
        obox[b * MAXDET + rk0] = o;
        areas[b * MAXDET + rk0] =
            __fmul_rn(__fadd_rn(__fsub_rn(o.z, o.x), 1.0f),
                      __fadd_rn(__fsub_rn(o.w, o.y), 1.0f));
    }
    if (k1) {
        float off1 = __fmul_rn((float)cl1, maxc1);
        float4 o = make_float4(__fadd_rn(v1.x, off1), __fadd_rn(v1.y, off1),
                               __fadd_rn(v1.z, off1), __fadd_rn(v1.w, off1));
        obox[b * MAXDET + rk1] = o;
        areas[b * MAXDET + rk1] =
            __fmul_rn(__fadd_rn(__fsub_rn(o.z, o.x), 1.0f),
                      __fadd_rn(__fsub_rn(o.w, o.y), 1.0f));
    }
}

// ---------------------------------------------------------------------------
// K4: suppression bits per (row i, 64-col word) + nonzero-row bitmap.
// ---------------------------------------------------------------------------
__global__ __launch_bounds__(256) void k_iou(const float4* obox, const float* areas,
                                             uint64_t* rows, uint64_t* nzmask) {
    __shared__ float4 ob[MAXDET];
    __shared__ float  ca[MAXDET];
    __shared__ uint64_t nzloc[16];
    int b = blockIdx.x, word = blockIdx.y, tid = threadIdx.x;
    if (tid < 16) nzloc[tid] = 0;
    for (int r = tid; r < MAXDET; r += 256) {
        ob[r] = obox[b * MAXDET + r];
        ca[r] = areas[b * MAXDET + r];
    }
    __syncthreads();

    int j0 = word * 64;
    int jlim = MAXDET - j0;
    if (jlim > 64) jlim = 64;

#pragma unroll
    for (int qr = 0; qr < 4; ++qr) {
        int i = tid + qr * 256;
        if (i >= MAXDET) continue;
        uint64_t rw = 0;
        int jmax = j0 + jlim;
        if (i < jmax - 1) {
            float4 bi = ob[i];
            float ai = ca[i];
            for (int jj = 0; jj < jlim; ++jj) {
                int j = j0 + jj;
                float4 bj = ob[j0 + jj];
                float xx1 = fmaxf(bi.x, bj.x), yy1 = fmaxf(bi.y, bj.y);
                float xx2 = fminf(bi.z, bj.z), yy2 = fminf(bi.w, bj.w);
                float w_ = fmaxf(__fsub_rn(xx2, xx1), 0.0f);
                float h_ = fmaxf(__fsub_rn(yy2, yy1), 0.0f);
                float inter = __fmul_rn(w_, h_);
                float denom = __fsub_rn(__fadd_rn(ai, ca[j0 + jj]), inter);
                bool sup = (j > i) && (inter > __fmul_rn(0.6f, denom));
                rw |= sup ? (1ull << jj) : 0ull;
            }
        }
        rows[((size_t)(b * MAXDET) + i) * 16 + word] = rw;
        if (rw) atomicOr(&nzloc[i >> 6], 1ull << (i & 63));
    }
    __syncthreads();
    if (tid < 16 && nzloc[tid])
        atomicOr(&nzmask[b * 16 + tid], nzloc[tid]);
}

// ---------------------------------------------------------------------------
// K5: sparse greedy scan. Rows are strictly upper-triangular, so
// keep = V & ~S_final, and only NONZERO rows (z-list) participate in the
// serial recurrence. Row z+1 prefetched from global one iteration ahead.
// ---------------------------------------------------------------------------
__global__ __launch_bounds__(256) void k_nms_out(const uint64_t* rows,
                                                 const uint64_t* nzmask,
                                                 const float* topk_score,
                                                 const int* gcls, const float4* gbox,
                                                 float* out) {
    __shared__ uint64_t validmask[16];
    __shared__ uint64_t keepmask[16];
    __shared__ int zlist[MAXDET];
    __shared__ int m_sh;
    int b = blockIdx.x, tid = threadIdx.x;

    if (tid < 16) validmask[tid] = 0;
    if (tid == 0) m_sh = 0;
    __syncthreads();
    for (int r = tid; r < MAXDET; r += 256)
        if (topk_score[b * MAXDET + r] >= 0.05f)
            atomicOr(&validmask[r >> 6], 1ull << (r & 63));
    if (tid == 0) {                          // ascending z-list of nonzero rows
        int m = 0;
        for (int w = 0; w < 16; ++w) {
            uint64_t nz = nzmask[b * 16 + w];
            while (nz) {
                int bit = __ffsll((unsigned long long)nz) - 1;
                nz &= nz - 1;
                zlist[m++] = w * 64 + bit;
            }
        }
        m_sh = m;
    }
    __syncthreads();

    int m = m_sh;
    uint64_t S = 0, V = 0;
    if (tid < 16) V = validmask[tid];
    if (tid < 64) {                          // wave 0 only
        const uint64_t* rg = rows + (size_t)b * MAXDET * 16;
        uint64_t row_nxt = 0;
        if (m > 0 && tid < 16) row_nxt = rg[(size_t)zlist[0] * 16 + tid];
        for (int k = 0; k < m; ++k) {
            uint64_t row_cur = row_nxt;
            if (k + 1 < m && tid < 16)
                row_nxt = rg[(size_t)zlist[k + 1] * 16 + tid];
            int z = zlist[k];
            int w = z >> 6, bp = z & 63;
            uint32_t aliveV = ((uint32_t)(V >> bp) & ~(uint32_t)(S >> bp)) & 1u;
            uint32_t alive = (uint32_t)__builtin_amdgcn_readlane((int)aliveV, w);
            if (alive) S |= row_cur;
        }
    }
    if (tid < 16) keepmask[tid] = V & ~S;
    __syncthreads();

    for (int r = tid; r < MAXDET; r += 256) {
        bool keep = ((keepmask[r >> 6] >> (r & 63)) & 1ull) != 0;
        float sc = topk_score[b * MAXDET + r];
        int cl = gcls[b * MAXDET + r];
        float4 v = gbox[b * MAXDET + r];
        float c0 = fminf(fmaxf(v.x, 0.0f), 1023.0f);
        float c1 = fminf(fmaxf(v.y, 0.0f), 1023.0f);
        float c2 = fminf(fmaxf(v.z, 0.0f), 1023.0f);
        float c3 = fminf(fmaxf(v.w, 0.0f), 1023.0f);
        out[b * MAXDET + r] = keep ? sc : 0.0f;
        out[BATCH * MAXDET + b * MAXDET + r] = keep ? (float)cl : 0.0f;
        float4* op = (float4*)(out + 2 * BATCH * MAXDET) + (b * MAXDET + r);
        *op = keep ? make_float4(c0, c1, c2, c3) : make_float4(0.f, 0.f, 0.f, 0.f);
    }
}

// ---------------------------------------------------------------------------
extern "C" void kernel_launch(void* const* d_in, const int* in_sizes, int n_in,
                              void* d_out, int out_size, void* d_ws, size_t ws_size,
                              hipStream_t stream) {
    (void)in_sizes; (void)n_in; (void)out_size; (void)ws_size;

    LevelPtrs lp;
    for (int i = 0; i < 5; ++i) {
        lp.cls[i] = (const float*)d_in[3 * i + 0];
        lp.cnt[i] = (const float*)d_in[3 * i + 1];
        lp.reg[i] = (const float*)d_in[3 * i + 2];
    }

    char* ws = (char*)d_ws;
    float*    scores   = (float*)   (ws + 0);          // 8*21824*4   = 698368
    int*      cls_ws   = (int*)     (ws + 698368);     // 698368
    float4*   boxes    = (float4*)  (ws + 1396736);    // 8*21824*16  = 2793472
    float*    topk_sc  = (float*)   (ws + 4222208);    // 32000
    int*      gcls     = (int*)     (ws + 4254208);    // 32000
    float4*   gbox     = (float4*)  (ws + 4286208);    // 128000
    float4*   obox     = (float4*)  (ws + 4414208);    // 128000
    float*    areas    = (float*)   (ws + 4542208);    // 32000
    uint64_t* rows     = (uint64_t*)(ws + 4574208);    // 8*1000*16*8 = 1024000
    uint64_t* nzmask   = (uint64_t*)(ws + 5598208);    // 8*16*8      = 1024

    dim3 g1(171, BATCH);
    k_stage1<<<g1, 256, 0, stream>>>(lp, scores, cls_ws, boxes);

    k_select<<<BATCH, 1024, 0, stream>>>((const uint32_t*)scores, boxes, cls_ws,
                                         topk_sc, gbox, gcls, obox, areas, nzmask);

    dim3 g4(BATCH, 16);
    k_iou<<<g4, 256, 0, stream>>>(obox, areas, rows, nzmask);

    k_nms_out<<<BATCH, 256, 0, stream>>>(rows, nzmask, topk_sc, gcls, gbox,
                                         (float*)d_out);
}